// Round 2
// baseline (504.594 us; speedup 1.0000x reference)
//
#include <hip/hip_runtime.h>

// ============================================================================
// ExtraMHSA pipeline for MI355X (gfx950).  R7: fused attn, occupancy + LDS fix.
//
//   prep_all   : pos embeds, BN-fold weights->bf16, zero O/l
//   front_k    : x ->(regs) x1=silu(conv1) ->(LDS) q,k,v,p -> LT/RT/Vv/pT
//   fused_attn : flash-style, P never to HBM.  R7 changes vs R6:
//     - T transpose buffers ALIAS Rs (R-tile dead after score) -> LDS 66->32KB
//     - T layout stride 128 + XOR chunk swizzle (chunk ^= row&7): conflict-free
//       writes and b128 reads (was stride-136, 4-way write conflict)
//     - R staged via global_load_lds (dest = wave-uniform base + lane*16,
//       XOR-8 swizzle moved to per-lane GLOBAL source address) -> no reg temps
//     - KD=256: A-frags reloaded per K-half (32 live VGPR, not 64)
//     - lds_fence (sched_barrier(0)) removed; all LDS handoffs via
//       __syncthreads() -> compiler free to pipeline PV's V global loads
//     - __launch_bounds__(256,3): 3 blocks/CU x 4 waves = 12 waves/CU
//   final_k    : out = x + silu(bn(conv2(O1/l1))) + silu(bn(conv3(O2/l2)))
// ============================================================================

typedef unsigned short u16;
typedef __attribute__((ext_vector_type(8))) short bf16x8;   // 8 bf16 = 4 VGPRs
typedef __attribute__((ext_vector_type(4))) float f32x4;    // MFMA C/D frag
typedef __attribute__((ext_vector_type(4))) unsigned int u32x4;

#define HW 6400
#define BN_EPS 1e-5f

__device__ __forceinline__ u16 f2b(float f) {       // fp32 -> bf16 RNE
  unsigned u = __float_as_uint(f);
  u += 0x7fffu + ((u >> 16) & 1u);
  return (u16)(u >> 16);
}
__device__ __forceinline__ unsigned pack2(float a, float b) {
  return (unsigned)f2b(a) | ((unsigned)f2b(b) << 16);
}
__device__ __forceinline__ f32x4 MFMA(bf16x8 a, bf16x8 b, f32x4 c) {
  return __builtin_amdgcn_mfma_f32_16x16x32_bf16(a, b, c, 0, 0, 0);
}
__device__ __forceinline__ float silu_f(float y) {
  return y / (1.0f + __expf(-y));
}
__device__ __forceinline__ bf16x8 pack8(f32x4 lo, f32x4 hi, float sc) {
  union { bf16x8 v; uint4 u; } r;
  r.u.x = pack2(lo[0] * sc, lo[1] * sc);
  r.u.y = pack2(lo[2] * sc, lo[3] * sc);
  r.u.z = pack2(hi[0] * sc, hi[1] * sc);
  r.u.w = pack2(hi[2] * sc, hi[3] * sc);
  return r.v;
}
// async global->LDS, 16B per lane; dst must be wave-uniform base (HW adds
// lane*16), src is per-lane.
__device__ __forceinline__ void gload_lds16(const u16* src, u16* dst) {
  __builtin_amdgcn_global_load_lds(
      (const __attribute__((address_space(1))) void*)src,
      (__attribute__((address_space(3))) void*)dst, 16, 0, 0);
}

// ---------------------------------------------------------------------------
// prep_all: [0,80) pos embeds; [80,144) weight BN-fold; [144,176) zero O/l.
// ---------------------------------------------------------------------------
__global__ void prep_all(
    const float* __restrict__ rel_h, const float* __restrict__ rel_w,
    const float* __restrict__ ef_h, const float* __restrict__ ef_w,
    const float* __restrict__ w1, const float* __restrict__ g1, const float* __restrict__ b1,
    const float* __restrict__ m1, const float* __restrict__ v1,
    const float* __restrict__ w2, const float* __restrict__ g2, const float* __restrict__ b2,
    const float* __restrict__ m2, const float* __restrict__ v2,
    const float* __restrict__ w3, const float* __restrict__ g3, const float* __restrict__ b3,
    const float* __restrict__ m3, const float* __restrict__ v3,
    const float* __restrict__ wq, const float* __restrict__ bq,
    const float* __restrict__ wk, const float* __restrict__ bk,
    const float* __restrict__ wv, const float* __restrict__ bv,
    const float* __restrict__ wp, const float* __restrict__ bp,
    u16* __restrict__ LT, u16* __restrict__ efT, u16* __restrict__ efc,
    u16* __restrict__ w1b, float* __restrict__ b1e,
    u16* __restrict__ Wcat, float* __restrict__ bcat,
    u16* __restrict__ w2b, float* __restrict__ b2e,
    u16* __restrict__ w3b, float* __restrict__ b3e,
    float* __restrict__ Obuf, float* __restrict__ lbuf)
{
  const int b = blockIdx.x;
  const int t = threadIdx.x;
  if (b < 80) {
    const int h = b;
    const int c0 = (t & 63) * 2;
    const float rh0 = rel_h[c0 * 80 + h], rh1 = rel_h[(c0 + 1) * 80 + h];
    const float eh0 = ef_h[c0 * 80 + h], eh1 = ef_h[(c0 + 1) * 80 + h];
    for (int wcol = (t >> 6); wcol < 80; wcol += 4) {
      const int i = h * 80 + wcol;
      float rw0 = rel_w[c0 * 80 + wcol], rw1 = rel_w[(c0 + 1) * 80 + wcol];
      float ew0 = ef_w[c0 * 80 + wcol], ew1 = ef_w[(c0 + 1) * 80 + wcol];
      *(unsigned*)&LT[(size_t)i * 256 + 128 + c0] = pack2(rh0 + rw0, rh1 + rw1);
      float e0 = eh0 + ew0, e1 = eh1 + ew1;
      *(unsigned*)&efT[(size_t)i * 128 + c0] = pack2(e0, e1);
      efc[(size_t)c0 * HW + i] = f2b(e0);
      efc[(size_t)(c0 + 1) * HW + i] = f2b(e1);
    }
  } else if (b < 144) {
    const int tid = (b - 80) * 256 + t;
    const int stride = 64 * 256;
    for (int idx = tid; idx < 128 * 256; idx += stride) {
      int o = idx >> 8;
      float s = g1[o] * rsqrtf(v1[o] + BN_EPS);
      w1b[idx] = f2b(w1[idx] * s);
    }
    for (int idx = tid; idx < 128; idx += stride) {
      float s = g1[idx] * rsqrtf(v1[idx] + BN_EPS);
      b1e[idx] = b1[idx] - m1[idx] * s;
    }
    for (int idx = tid; idx < 4 * 128 * 128; idx += stride) {
      int which = idx >> 14, r = idx & 16383;
      const float* src = which == 0 ? wq : which == 1 ? wk : which == 2 ? wv : wp;
      Wcat[idx] = f2b(src[r]);
    }
    for (int idx = tid; idx < 512; idx += stride) {
      int which = idx >> 7, r = idx & 127;
      const float* src = which == 0 ? bq : which == 1 ? bk : which == 2 ? bv : bp;
      bcat[idx] = src[r];
    }
    for (int idx = tid; idx < 256 * 128; idx += stride) {
      int o = idx >> 7;
      float s2 = g2[o] * rsqrtf(v2[o] + BN_EPS);
      w2b[idx] = f2b(w2[idx] * s2);
      float s3 = g3[o] * rsqrtf(v3[o] + BN_EPS);
      w3b[idx] = f2b(w3[idx] * s3);
    }
    for (int idx = tid; idx < 256; idx += stride) {
      float s2 = g2[idx] * rsqrtf(v2[idx] + BN_EPS);
      b2e[idx] = b2[idx] - m2[idx] * s2;
      float s3 = g3[idx] * rsqrtf(v3[idx] + BN_EPS);
      b3e[idx] = b3[idx] - m3[idx] * s3;
    }
  } else {
    const int tid = (b - 144) * 256 + t;
    const int stride = 32 * 256;
    f32x4 z = {0.f, 0.f, 0.f, 0.f};
    for (int idx = tid; idx < 2 * HW * 128 / 4; idx += stride)
      ((f32x4*)Obuf)[idx] = z;
    for (int idx = tid; idx < 2 * HW / 4; idx += stride)
      ((f32x4*)lbuf)[idx] = z;
  }
}

// ---------------------------------------------------------------------------
// front_k: fused  x -> x1=silu(bn(conv1(x))) -> {q,k,v,p} -> LT/RT/Vv/pT.
// grid <<<200, 128>>>: 2 waves x 16 i-rows.
// ---------------------------------------------------------------------------
__global__ __launch_bounds__(128) void front_k(
    const float* __restrict__ x,
    const u16* __restrict__ w1b, const float* __restrict__ b1e,
    const u16* __restrict__ Wcat, const float* __restrict__ bcat,
    u16* __restrict__ LT, u16* __restrict__ RT, u16* __restrict__ Vv,
    u16* __restrict__ pT)
{
  __shared__ __align__(16) u16 tr[2][16][136];
  const int t = threadIdx.x, w = t >> 6, lane = t & 63, jl = lane & 15, q = lane >> 4;
  const int i0 = blockIdx.x * 32 + w * 16;

  bf16x8 afr[8];
#pragma unroll
  for (int ks = 0; ks < 8; ++ks) {
    union { bf16x8 v; u16 e[8]; } fa;
#pragma unroll
    for (int e = 0; e < 8; ++e)
      fa.e[e] = f2b(x[(size_t)(ks * 32 + q * 8 + e) * HW + i0 + jl]);
    afr[ks] = fa.v;
  }
  f32x4 acc[8];
#pragma unroll
  for (int nf = 0; nf < 8; ++nf) acc[nf] = (f32x4){0.f, 0.f, 0.f, 0.f};
#pragma unroll
  for (int ks = 0; ks < 8; ++ks)
#pragma unroll
    for (int nf = 0; nf < 8; ++nf) {
      bf16x8 b = *(const bf16x8*)(w1b + (size_t)(nf * 16 + jl) * 256 + ks * 32 + q * 8);
      acc[nf] = MFMA(afr[ks], b, acc[nf]);
    }
#pragma unroll
  for (int nf = 0; nf < 8; ++nf) {
    const int c = nf * 16 + jl;
    const float bias = b1e[c];
#pragma unroll
    for (int r = 0; r < 4; ++r)
      tr[w][q * 4 + r][c] = f2b(silu_f(acc[nf][r] + bias));
  }
  __syncthreads();
  bf16x8 xa[4];
#pragma unroll
  for (int ks = 0; ks < 4; ++ks)
    xa[ks] = *(const bf16x8*)&tr[w][jl][ks * 32 + q * 8];

#pragma unroll
  for (int nc = 0; nc < 4; ++nc) {
    f32x4 a2[8];
#pragma unroll
    for (int nf = 0; nf < 8; ++nf) a2[nf] = (f32x4){0.f, 0.f, 0.f, 0.f};
#pragma unroll
    for (int ks = 0; ks < 4; ++ks)
#pragma unroll
      for (int nf = 0; nf < 8; ++nf) {
        bf16x8 b = *(const bf16x8*)(Wcat + (size_t)(nc * 128 + nf * 16 + jl) * 128 + ks * 32 + q * 8);
        a2[nf] = MFMA(xa[ks], b, a2[nf]);
      }
    if (nc == 2) {
#pragma unroll
      for (int nf = 0; nf < 8; ++nf) {
        const int c = nf * 16 + jl;
        const float bias = bcat[256 + c];
        uint2 pk;
        pk.x = pack2(a2[nf][0] + bias, a2[nf][1] + bias);
        pk.y = pack2(a2[nf][2] + bias, a2[nf][3] + bias);
        *(uint2*)(Vv + (size_t)c * HW + i0 + q * 4) = pk;
      }
    } else {
      __syncthreads();
#pragma unroll
      for (int nf = 0; nf < 8; ++nf) {
        const int c = nf * 16 + jl;
        const float bias = bcat[nc * 128 + c];
#pragma unroll
        for (int r = 0; r < 4; ++r)
          tr[w][q * 4 + r][c] = f2b(a2[nf][r] + bias);
      }
      __syncthreads();
#pragma unroll
      for (int r = 0; r < 16; ++r) {
        unsigned val = *(const unsigned*)&tr[w][r][lane * 2];
        const size_t row = (size_t)(i0 + r);
        if (nc == 0) {
          *(unsigned*)(LT + row * 256 + lane * 2) = val;
          *(unsigned*)(RT + row * 256 + 128 + lane * 2) = val;
        } else if (nc == 1) {
          *(unsigned*)(RT + row * 256 + lane * 2) = val;
        } else {
          *(unsigned*)(pT + row * 128 + lane * 2) = val;
        }
      }
    }
  }
}

// ---------------------------------------------------------------------------
// fused_attn body.  LDS = one 32KB buffer Rs:
//   during score: R-tile [128 j][128 k] (XOR-8 chunk swizzle, staged via
//     global_load_lds with pre-swizzled per-lane source)
//   after score:  4 waves x 2 T-buffers [16 i][128 j] u16, stride 128,
//     chunk-XOR swizzle (chunk ^= row&7) -> conflict-free write + b128 read.
// All handoffs via __syncthreads().
// ---------------------------------------------------------------------------
template <int KD>
__device__ __forceinline__ void attn_body(
    const u16* __restrict__ Lt,     // [HW][KD]
    const u16* __restrict__ Rt,     // [HW][KD]
    const u16* __restrict__ Vm,     // [128][HW]
    float* __restrict__ O,          // [HW][128]
    float* __restrict__ lv,         // [HW]
    int bid, u16* __restrict__ Rs)
{
  const int t = threadIdx.x, lane = t & 63, w = t >> 6, jl = lane & 15, q = lane >> 4;
  const int it = bid / 10, jp = bid % 10;
  const int i0w = it * 128 + w * 32;
  u16* T0 = Rs + w * 4096;                       // [16][128] u16
  u16* T1 = T0 + 2048;

  // KD=128: A-frags resident (32 VGPR).  KD=256: reloaded per K-half.
  bf16x8 afr128[2][4];
  if constexpr (KD == 128) {
#pragma unroll
    for (int mt = 0; mt < 2; ++mt)
#pragma unroll
      for (int l = 0; l < 4; ++l)
        afr128[mt][l] = *(const bf16x8*)(Lt + (size_t)(i0w + mt * 16 + jl) * KD + l * 32 + q * 8);
  }

  f32x4 o[2][8];
#pragma unroll
  for (int mt = 0; mt < 2; ++mt)
#pragma unroll
    for (int cf = 0; cf < 8; ++cf) o[mt][cf] = (f32x4){0.f, 0.f, 0.f, 0.f};
  float lacc[2][4] = {{0.f, 0.f, 0.f, 0.f}, {0.f, 0.f, 0.f, 0.f}};

  for (int stp = 0; stp < 5; ++stp) {
    const int jj = jp * 640 + stp * 128;

    f32x4 s[2][8];
#pragma unroll
    for (int mt = 0; mt < 2; ++mt)
#pragma unroll
      for (int nf = 0; nf < 8; ++nf) s[mt][nf] = (f32x4){0.f, 0.f, 0.f, 0.f};

    // ---- score: S = L . R^T over K halves of 128
#pragma unroll
    for (int h = 0; h < KD / 128; ++h) {
      __syncthreads();                           // prior Rs readers done
#pragma unroll
      for (int cc = 0; cc < 8; ++cc) {
        const int jr = w * 32 + cc * 4 + (lane >> 4);
        const int cp = lane & 15;
        const int ch = (cp & ~7) | ((cp ^ jr) & 7);
        gload_lds16(Rt + (size_t)(jj + jr) * KD + h * 128 + ch * 8,
                    Rs + ((w * 8 + cc) << 9));
      }
      __syncthreads();                           // stage complete (vmcnt drain)

      bf16x8 ah[2][4];
      if constexpr (KD == 256) {
#pragma unroll
        for (int mt = 0; mt < 2; ++mt)
#pragma unroll
          for (int l = 0; l < 4; ++l)
            ah[mt][l] = *(const bf16x8*)(Lt + (size_t)(i0w + mt * 16 + jl) * KD + h * 128 + l * 32 + q * 8);
      } else {
#pragma unroll
        for (int mt = 0; mt < 2; ++mt)
#pragma unroll
          for (int l = 0; l < 4; ++l)
            ah[mt][l] = afr128[mt][l];
      }
#pragma unroll
      for (int nf = 0; nf < 8; ++nf) {
        const int row = nf * 16 + jl;
#pragma unroll
        for (int l = 0; l < 4; ++l) {
          const int ch = (l * 4 + q) ^ (jl & 7); // un-swizzle
          bf16x8 b = *(const bf16x8*)(Rs + row * 128 + ch * 8);
          s[0][nf] = MFMA(ah[0][l], b, s[0][nf]);
          s[1][nf] = MFMA(ah[1][l], b, s[1][nf]);
        }
      }
    }

    // ---- P = exp(S); accumulate rowsums in registers
#pragma unroll
    for (int mt = 0; mt < 2; ++mt)
#pragma unroll
      for (int nf = 0; nf < 8; ++nf)
#pragma unroll
        for (int r = 0; r < 4; ++r) {
          float p = __expf(s[mt][nf][r]);
          s[mt][nf][r] = p;
          lacc[mt][r] += p;
        }

    __syncthreads();                             // score Rs reads done
    // ---- transpose P C-frags -> T buffers (aliasing Rs), chunk-XOR swizzle
#pragma unroll
    for (int nf = 0; nf < 8; ++nf)
#pragma unroll
      for (int r = 0; r < 4; ++r) {
        const int row = q * 4 + r;
        const int chs = (nf * 2 + (jl >> 3)) ^ (row & 7);
        T0[row * 128 + chs * 8 + (jl & 7)] = f2b(s[0][nf][r]);
        T1[row * 128 + chs * 8 + (jl & 7)] = f2b(s[1][nf][r]);
      }
    __syncthreads();                             // T visible

    // ---- PV: O += P . V^T, V B-frags direct from global (L1/L2-resident)
#pragma unroll
    for (int ks2 = 0; ks2 < 4; ++ks2) {
      const int kcs = ((ks2 * 4 + q) ^ (jl & 7)) * 8;
      bf16x8 pa0 = *(const bf16x8*)(T0 + jl * 128 + kcs);
      bf16x8 pa1 = *(const bf16x8*)(T1 + jl * 128 + kcs);
#pragma unroll
      for (int cf = 0; cf < 8; ++cf) {
        bf16x8 bv = *(const bf16x8*)(Vm + (size_t)(cf * 16 + jl) * HW + jj + ks2 * 32 + q * 8);
        o[0][cf] = MFMA(pa0, bv, o[0][cf]);
        o[1][cf] = MFMA(pa1, bv, o[1][cf]);
      }
    }
  }

  // ---- epilogue: l rowsum reduce + atomics, O atomics (L2-resident)
#pragma unroll
  for (int mt = 0; mt < 2; ++mt) {
    float rs[4] = {lacc[mt][0], lacc[mt][1], lacc[mt][2], lacc[mt][3]};
#pragma unroll
    for (int d = 1; d < 16; d <<= 1)
#pragma unroll
      for (int r = 0; r < 4; ++r) rs[r] += __shfl_xor(rs[r], d);
    if (jl == 0) {
#pragma unroll
      for (int r = 0; r < 4; ++r)
        atomicAdd(&lv[i0w + mt * 16 + q * 4 + r], rs[r]);
    }
  }
#pragma unroll
  for (int mt = 0; mt < 2; ++mt) {
    const int ib = i0w + mt * 16 + q * 4;
#pragma unroll
    for (int cf = 0; cf < 8; ++cf) {
      const int c = cf * 16 + jl;
#pragma unroll
      for (int r = 0; r < 4; ++r)
        atomicAdd(&O[(size_t)(ib + r) * 128 + c], o[mt][cf][r]);
    }
  }
}

// grid <<<1000, 256>>>: bid<500 head1 (KD=256), else head2 (KD=128).
// LDS: 32KB (Rs, T-buffers aliased in) -> 3 blocks/CU (VGPR-capped by
// launch_bounds(256,3): <=170 regs), 12 waves/CU.
__global__ __launch_bounds__(256, 3) void fused_attn(
    const u16* __restrict__ LT, const u16* __restrict__ RT, const u16* __restrict__ Vv,
    const u16* __restrict__ pT, const u16* __restrict__ efT, const u16* __restrict__ efc,
    float* __restrict__ Obuf, float* __restrict__ lbuf)
{
  __shared__ __align__(1024) u16 Rs[128 * 128];
  const int bid = blockIdx.x;
  if (bid < 500)
    attn_body<256>(LT, RT, Vv, Obuf, lbuf, bid, Rs);
  else
    attn_body<128>(pT, efT, efc, Obuf + (size_t)HW * 128, lbuf + HW, bid - 500, Rs);
}

// ---------------------------------------------------------------------------
// final_k: out[d][i] = x[d][i] + silu(o1.w2b + b2e) + silu(o2.w3b + b3e),
// o?[i][c] = O[h][i][c] / l[h][i], built as bf16 A-frags on the fly.
// grid dim3(100, 2), 256 thr.
// ---------------------------------------------------------------------------
__global__ __launch_bounds__(256) void final_k(
    const float* __restrict__ Obuf,    // [2][HW][128]
    const float* __restrict__ lbuf,    // [2][HW]
    const u16* __restrict__ w2b, const float* __restrict__ b2e,
    const u16* __restrict__ w3b, const float* __restrict__ b3e,
    const float* __restrict__ x, float* __restrict__ outp)
{
  const int t = threadIdx.x, w = t >> 6, lane = t & 63, jl = lane & 15, q = lane >> 4;
  const int i0 = blockIdx.x * 64 + w * 16;
  const int nc = blockIdx.y;
  const int row = i0 + jl;

  const float inv1 = 1.0f / lbuf[row];
  const float inv2 = 1.0f / lbuf[HW + row];
  const float* O1 = Obuf + (size_t)row * 128;
  const float* O2 = Obuf + (size_t)(HW + row) * 128;

  f32x4 a1[8], a2[8];
#pragma unroll
  for (int nf = 0; nf < 8; ++nf) {
    a1[nf] = (f32x4){0.f, 0.f, 0.f, 0.f};
    a2[nf] = (f32x4){0.f, 0.f, 0.f, 0.f};
  }
#pragma unroll
  for (int ks = 0; ks < 4; ++ks) {
    f32x4 s1a = *(const f32x4*)(O1 + ks * 32 + q * 8);
    f32x4 s1b = *(const f32x4*)(O1 + ks * 32 + q * 8 + 4);
    f32x4 s2a = *(const f32x4*)(O2 + ks * 32 + q * 8);
    f32x4 s2b = *(const f32x4*)(O2 + ks * 32 + q * 8 + 4);
    bf16x8 fa1 = pack8(s1a, s1b, inv1);
    bf16x8 fa2 = pack8(s2a, s2b, inv2);
#pragma unroll
    for (int nf = 0; nf < 8; ++nf) {
      bf16x8 b2f = *(const bf16x8*)(w2b + (size_t)(nc * 128 + nf * 16 + jl) * 128 + ks * 32 + q * 8);
      bf16x8 b3f = *(const bf16x8*)(w3b + (size_t)(nc * 128 + nf * 16 + jl) * 128 + ks * 32 + q * 8);
      a1[nf] = MFMA(fa1, b2f, a1[nf]);
      a2[nf] = MFMA(fa2, b3f, a2[nf]);
    }
  }
#pragma unroll
  for (int nf = 0; nf < 8; ++nf) {
    const int d = nc * 128 + nf * 16 + jl;
    const float bb2 = b2e[d], bb3 = b3e[d];
    const size_t base = (size_t)d * HW + i0 + q * 4;
    f32x4 xv = *(const f32x4*)(x + base);
    f32x4 rv;
#pragma unroll
    for (int r = 0; r < 4; ++r)
      rv[r] = xv[r] + silu_f(a1[nf][r] + bb2) + silu_f(a2[nf][r] + bb3);
    *(f32x4*)(outp + base) = rv;
  }
}

// ---------------------------------------------------------------------------
extern "C" void kernel_launch(void* const* d_in, const int* in_sizes, int n_in,
                              void* d_out, int out_size, void* d_ws, size_t ws_size,
                              hipStream_t stream)
{
  (void)in_sizes; (void)n_in; (void)out_size; (void)ws_size;
  const float* x   = (const float*)d_in[0];
  const float* w1  = (const float*)d_in[1];
  const float* g1  = (const float*)d_in[2];
  const float* b1  = (const float*)d_in[3];
  const float* m1  = (const float*)d_in[4];
  const float* v1  = (const float*)d_in[5];
  const float* w2  = (const float*)d_in[6];
  const float* g2  = (const float*)d_in[7];
  const float* b2  = (const float*)d_in[8];
  const float* m2  = (const float*)d_in[9];
  const float* v2  = (const float*)d_in[10];
  const float* w3  = (const float*)d_in[11];
  const float* g3  = (const float*)d_in[12];
  const float* b3  = (const float*)d_in[13];
  const float* m3  = (const float*)d_in[14];
  const float* v3  = (const float*)d_in[15];
  const float* wq  = (const float*)d_in[16];
  const float* bq  = (const float*)d_in[17];
  const float* wk  = (const float*)d_in[18];
  const float* bk  = (const float*)d_in[19];
  const float* wv  = (const float*)d_in[20];
  const float* bv  = (const float*)d_in[21];
  const float* wp  = (const float*)d_in[22];
  const float* bp  = (const float*)d_in[23];
  const float* rel_h = (const float*)d_in[24];
  const float* rel_w = (const float*)d_in[25];
  const float* ef_h  = (const float*)d_in[26];
  const float* ef_w  = (const float*)d_in[27];
  float* outp = (float*)d_out;

  char* ws = (char*)d_ws;
  size_t off = 0;
  auto alloc = [&](size_t bytes) -> void* {
    void* p = ws + off;
    off += (bytes + 511) & ~(size_t)511;
    return p;
  };
  u16* LT    = (u16*)alloc((size_t)HW * 256 * 2);
  u16* RT    = (u16*)alloc((size_t)HW * 256 * 2);
  u16* pT    = (u16*)alloc((size_t)HW * 128 * 2);
  u16* efT   = (u16*)alloc((size_t)HW * 128 * 2);
  u16* efc   = (u16*)alloc((size_t)HW * 128 * 2);
  u16* Vv    = (u16*)alloc((size_t)HW * 128 * 2);
  float* Obuf = (float*)alloc((size_t)2 * HW * 128 * 4);    // 6.55 MB
  float* lbuf = (float*)alloc((size_t)2 * HW * 4);
  u16* w1b   = (u16*)alloc(128 * 256 * 2);
  float* b1e = (float*)alloc(128 * 4);
  u16* Wcat  = (u16*)alloc(512 * 128 * 2);
  float* bcat = (float*)alloc(512 * 4);
  u16* w2b   = (u16*)alloc(256 * 128 * 2);
  float* b2e = (float*)alloc(256 * 4);
  u16* w3b   = (u16*)alloc(256 * 128 * 2);
  float* b3e = (float*)alloc(256 * 4);

  prep_all<<<176, 256, 0, stream>>>(rel_h, rel_w, ef_h, ef_w,
                                    w1, g1, b1, m1, v1, w2, g2, b2, m2, v2,
                                    w3, g3, b3, m3, v3, wq, bq, wk, bk, wv, bv, wp, bp,
                                    LT, efT, efc,
                                    w1b, b1e, Wcat, bcat, w2b, b2e, w3b, b3e,
                                    Obuf, lbuf);
  front_k<<<200, 128, 0, stream>>>(x, w1b, b1e, Wcat, bcat, LT, RT, Vv, pT);
  fused_attn<<<1000, 256, 0, stream>>>(LT, RT, Vv, pT, efT, efc, Obuf, lbuf);
  final_k<<<dim3(100, 2), 256, 0, stream>>>(Obuf, lbuf, w2b, b2e, w3b, b3e, x, outp);
}

// Round 3
// 336.086 us; speedup vs baseline: 1.5014x; 1.5014x over previous
//
#include <hip/hip_runtime.h>

// ============================================================================
// ExtraMHSA pipeline for MI355X (gfx950).  R8: R7 structure, spill fix.
//
//   prep_all   : pos embeds, BN-fold weights->bf16, zero O/l
//   front_k    : x ->(regs) x1=silu(conv1) ->(LDS) q,k,v,p -> LT/RT/Vv/pT
//   fused_attn : flash-style, P never to HBM.
//     - T transpose buffers ALIAS Rs (R-tile dead after score) -> LDS 32KB
//     - T layout stride 128 + XOR chunk swizzle (chunk ^= row&7)
//     - R staged via global_load_lds (XOR-8 swizzle on per-lane GLOBAL src)
//     - KD=256: A-frags reloaded per K-half (32 live VGPR, not 64)
//     - __launch_bounds__(256, 2):  R7's (256,3) capped VGPR below the live
//       set (VGPR_Count fell to 84, scratch spill added ~600MB HBM traffic,
//       MfmaUtil 6%).  (256,2) lets the allocator land at its natural ~128
//       (R6 measured exactly 128, no spill); with LDS at 32KB the occupancy
//       limiter becomes VGPR: 128 -> 4 blocks/CU = 16 waves/CU (50%).
//   final_k    : out = x + silu(bn(conv2(O1/l1))) + silu(bn(conv3(O2/l2)))
// ============================================================================

typedef unsigned short u16;
typedef __attribute__((ext_vector_type(8))) short bf16x8;   // 8 bf16 = 4 VGPRs
typedef __attribute__((ext_vector_type(4))) float f32x4;    // MFMA C/D frag
typedef __attribute__((ext_vector_type(4))) unsigned int u32x4;

#define HW 6400
#define BN_EPS 1e-5f

__device__ __forceinline__ u16 f2b(float f) {       // fp32 -> bf16 RNE
  unsigned u = __float_as_uint(f);
  u += 0x7fffu + ((u >> 16) & 1u);
  return (u16)(u >> 16);
}
__device__ __forceinline__ unsigned pack2(float a, float b) {
  return (unsigned)f2b(a) | ((unsigned)f2b(b) << 16);
}
__device__ __forceinline__ f32x4 MFMA(bf16x8 a, bf16x8 b, f32x4 c) {
  return __builtin_amdgcn_mfma_f32_16x16x32_bf16(a, b, c, 0, 0, 0);
}
__device__ __forceinline__ float silu_f(float y) {
  return y / (1.0f + __expf(-y));
}
__device__ __forceinline__ bf16x8 pack8(f32x4 lo, f32x4 hi, float sc) {
  union { bf16x8 v; uint4 u; } r;
  r.u.x = pack2(lo[0] * sc, lo[1] * sc);
  r.u.y = pack2(lo[2] * sc, lo[3] * sc);
  r.u.z = pack2(hi[0] * sc, hi[1] * sc);
  r.u.w = pack2(hi[2] * sc, hi[3] * sc);
  return r.v;
}
// async global->LDS, 16B per lane; dst must be wave-uniform base (HW adds
// lane*16), src is per-lane.
__device__ __forceinline__ void gload_lds16(const u16* src, u16* dst) {
  __builtin_amdgcn_global_load_lds(
      (const __attribute__((address_space(1))) void*)src,
      (__attribute__((address_space(3))) void*)dst, 16, 0, 0);
}

// ---------------------------------------------------------------------------
// prep_all: [0,80) pos embeds; [80,144) weight BN-fold; [144,176) zero O/l.
// ---------------------------------------------------------------------------
__global__ void prep_all(
    const float* __restrict__ rel_h, const float* __restrict__ rel_w,
    const float* __restrict__ ef_h, const float* __restrict__ ef_w,
    const float* __restrict__ w1, const float* __restrict__ g1, const float* __restrict__ b1,
    const float* __restrict__ m1, const float* __restrict__ v1,
    const float* __restrict__ w2, const float* __restrict__ g2, const float* __restrict__ b2,
    const float* __restrict__ m2, const float* __restrict__ v2,
    const float* __restrict__ w3, const float* __restrict__ g3, const float* __restrict__ b3,
    const float* __restrict__ m3, const float* __restrict__ v3,
    const float* __restrict__ wq, const float* __restrict__ bq,
    const float* __restrict__ wk, const float* __restrict__ bk,
    const float* __restrict__ wv, const float* __restrict__ bv,
    const float* __restrict__ wp, const float* __restrict__ bp,
    u16* __restrict__ LT, u16* __restrict__ efT, u16* __restrict__ efc,
    u16* __restrict__ w1b, float* __restrict__ b1e,
    u16* __restrict__ Wcat, float* __restrict__ bcat,
    u16* __restrict__ w2b, float* __restrict__ b2e,
    u16* __restrict__ w3b, float* __restrict__ b3e,
    float* __restrict__ Obuf, float* __restrict__ lbuf)
{
  const int b = blockIdx.x;
  const int t = threadIdx.x;
  if (b < 80) {
    const int h = b;
    const int c0 = (t & 63) * 2;
    const float rh0 = rel_h[c0 * 80 + h], rh1 = rel_h[(c0 + 1) * 80 + h];
    const float eh0 = ef_h[c0 * 80 + h], eh1 = ef_h[(c0 + 1) * 80 + h];
    for (int wcol = (t >> 6); wcol < 80; wcol += 4) {
      const int i = h * 80 + wcol;
      float rw0 = rel_w[c0 * 80 + wcol], rw1 = rel_w[(c0 + 1) * 80 + wcol];
      float ew0 = ef_w[c0 * 80 + wcol], ew1 = ef_w[(c0 + 1) * 80 + wcol];
      *(unsigned*)&LT[(size_t)i * 256 + 128 + c0] = pack2(rh0 + rw0, rh1 + rw1);
      float e0 = eh0 + ew0, e1 = eh1 + ew1;
      *(unsigned*)&efT[(size_t)i * 128 + c0] = pack2(e0, e1);
      efc[(size_t)c0 * HW + i] = f2b(e0);
      efc[(size_t)(c0 + 1) * HW + i] = f2b(e1);
    }
  } else if (b < 144) {
    const int tid = (b - 80) * 256 + t;
    const int stride = 64 * 256;
    for (int idx = tid; idx < 128 * 256; idx += stride) {
      int o = idx >> 8;
      float s = g1[o] * rsqrtf(v1[o] + BN_EPS);
      w1b[idx] = f2b(w1[idx] * s);
    }
    for (int idx = tid; idx < 128; idx += stride) {
      float s = g1[idx] * rsqrtf(v1[idx] + BN_EPS);
      b1e[idx] = b1[idx] - m1[idx] * s;
    }
    for (int idx = tid; idx < 4 * 128 * 128; idx += stride) {
      int which = idx >> 14, r = idx & 16383;
      const float* src = which == 0 ? wq : which == 1 ? wk : which == 2 ? wv : wp;
      Wcat[idx] = f2b(src[r]);
    }
    for (int idx = tid; idx < 512; idx += stride) {
      int which = idx >> 7, r = idx & 127;
      const float* src = which == 0 ? bq : which == 1 ? bk : which == 2 ? bv : bp;
      bcat[idx] = src[r];
    }
    for (int idx = tid; idx < 256 * 128; idx += stride) {
      int o = idx >> 7;
      float s2 = g2[o] * rsqrtf(v2[o] + BN_EPS);
      w2b[idx] = f2b(w2[idx] * s2);
      float s3 = g3[o] * rsqrtf(v3[o] + BN_EPS);
      w3b[idx] = f2b(w3[idx] * s3);
    }
    for (int idx = tid; idx < 256; idx += stride) {
      float s2 = g2[idx] * rsqrtf(v2[idx] + BN_EPS);
      b2e[idx] = b2[idx] - m2[idx] * s2;
      float s3 = g3[idx] * rsqrtf(v3[idx] + BN_EPS);
      b3e[idx] = b3[idx] - m3[idx] * s3;
    }
  } else {
    const int tid = (b - 144) * 256 + t;
    const int stride = 32 * 256;
    f32x4 z = {0.f, 0.f, 0.f, 0.f};
    for (int idx = tid; idx < 2 * HW * 128 / 4; idx += stride)
      ((f32x4*)Obuf)[idx] = z;
    for (int idx = tid; idx < 2 * HW / 4; idx += stride)
      ((f32x4*)lbuf)[idx] = z;
  }
}

// ---------------------------------------------------------------------------
// front_k: fused  x -> x1=silu(bn(conv1(x))) -> {q,k,v,p} -> LT/RT/Vv/pT.
// grid <<<200, 128>>>: 2 waves x 16 i-rows.
// ---------------------------------------------------------------------------
__global__ __launch_bounds__(128) void front_k(
    const float* __restrict__ x,
    const u16* __restrict__ w1b, const float* __restrict__ b1e,
    const u16* __restrict__ Wcat, const float* __restrict__ bcat,
    u16* __restrict__ LT, u16* __restrict__ RT, u16* __restrict__ Vv,
    u16* __restrict__ pT)
{
  __shared__ __align__(16) u16 tr[2][16][136];
  const int t = threadIdx.x, w = t >> 6, lane = t & 63, jl = lane & 15, q = lane >> 4;
  const int i0 = blockIdx.x * 32 + w * 16;

  bf16x8 afr[8];
#pragma unroll
  for (int ks = 0; ks < 8; ++ks) {
    union { bf16x8 v; u16 e[8]; } fa;
#pragma unroll
    for (int e = 0; e < 8; ++e)
      fa.e[e] = f2b(x[(size_t)(ks * 32 + q * 8 + e) * HW + i0 + jl]);
    afr[ks] = fa.v;
  }
  f32x4 acc[8];
#pragma unroll
  for (int nf = 0; nf < 8; ++nf) acc[nf] = (f32x4){0.f, 0.f, 0.f, 0.f};
#pragma unroll
  for (int ks = 0; ks < 8; ++ks)
#pragma unroll
    for (int nf = 0; nf < 8; ++nf) {
      bf16x8 b = *(const bf16x8*)(w1b + (size_t)(nf * 16 + jl) * 256 + ks * 32 + q * 8);
      acc[nf] = MFMA(afr[ks], b, acc[nf]);
    }
#pragma unroll
  for (int nf = 0; nf < 8; ++nf) {
    const int c = nf * 16 + jl;
    const float bias = b1e[c];
#pragma unroll
    for (int r = 0; r < 4; ++r)
      tr[w][q * 4 + r][c] = f2b(silu_f(acc[nf][r] + bias));
  }
  __syncthreads();
  bf16x8 xa[4];
#pragma unroll
  for (int ks = 0; ks < 4; ++ks)
    xa[ks] = *(const bf16x8*)&tr[w][jl][ks * 32 + q * 8];

#pragma unroll
  for (int nc = 0; nc < 4; ++nc) {
    f32x4 a2[8];
#pragma unroll
    for (int nf = 0; nf < 8; ++nf) a2[nf] = (f32x4){0.f, 0.f, 0.f, 0.f};
#pragma unroll
    for (int ks = 0; ks < 4; ++ks)
#pragma unroll
      for (int nf = 0; nf < 8; ++nf) {
        bf16x8 b = *(const bf16x8*)(Wcat + (size_t)(nc * 128 + nf * 16 + jl) * 128 + ks * 32 + q * 8);
        a2[nf] = MFMA(xa[ks], b, a2[nf]);
      }
    if (nc == 2) {
#pragma unroll
      for (int nf = 0; nf < 8; ++nf) {
        const int c = nf * 16 + jl;
        const float bias = bcat[256 + c];
        uint2 pk;
        pk.x = pack2(a2[nf][0] + bias, a2[nf][1] + bias);
        pk.y = pack2(a2[nf][2] + bias, a2[nf][3] + bias);
        *(uint2*)(Vv + (size_t)c * HW + i0 + q * 4) = pk;
      }
    } else {
      __syncthreads();
#pragma unroll
      for (int nf = 0; nf < 8; ++nf) {
        const int c = nf * 16 + jl;
        const float bias = bcat[nc * 128 + c];
#pragma unroll
        for (int r = 0; r < 4; ++r)
          tr[w][q * 4 + r][c] = f2b(a2[nf][r] + bias);
      }
      __syncthreads();
#pragma unroll
      for (int r = 0; r < 16; ++r) {
        unsigned val = *(const unsigned*)&tr[w][r][lane * 2];
        const size_t row = (size_t)(i0 + r);
        if (nc == 0) {
          *(unsigned*)(LT + row * 256 + lane * 2) = val;
          *(unsigned*)(RT + row * 256 + 128 + lane * 2) = val;
        } else if (nc == 1) {
          *(unsigned*)(RT + row * 256 + lane * 2) = val;
        } else {
          *(unsigned*)(pT + row * 128 + lane * 2) = val;
        }
      }
    }
  }
}

// ---------------------------------------------------------------------------
// fused_attn body.  LDS = one 32KB buffer Rs:
//   during score: R-tile [128 j][128 k] (XOR-8 chunk swizzle, staged via
//     global_load_lds with pre-swizzled per-lane source)
//   after score:  4 waves x 2 T-buffers [16 i][128 j] u16, stride 128,
//     chunk-XOR swizzle (chunk ^= row&7).
// All handoffs via __syncthreads().
// ---------------------------------------------------------------------------
template <int KD>
__device__ __forceinline__ void attn_body(
    const u16* __restrict__ Lt,     // [HW][KD]
    const u16* __restrict__ Rt,     // [HW][KD]
    const u16* __restrict__ Vm,     // [128][HW]
    float* __restrict__ O,          // [HW][128]
    float* __restrict__ lv,         // [HW]
    int bid, u16* __restrict__ Rs)
{
  const int t = threadIdx.x, lane = t & 63, w = t >> 6, jl = lane & 15, q = lane >> 4;
  const int it = bid / 10, jp = bid % 10;
  const int i0w = it * 128 + w * 32;
  u16* T0 = Rs + w * 4096;                       // [16][128] u16
  u16* T1 = T0 + 2048;

  // KD=128: A-frags resident (32 VGPR).  KD=256: reloaded per K-half.
  bf16x8 afr128[2][4];
  if constexpr (KD == 128) {
#pragma unroll
    for (int mt = 0; mt < 2; ++mt)
#pragma unroll
      for (int l = 0; l < 4; ++l)
        afr128[mt][l] = *(const bf16x8*)(Lt + (size_t)(i0w + mt * 16 + jl) * KD + l * 32 + q * 8);
  }

  f32x4 o[2][8];
#pragma unroll
  for (int mt = 0; mt < 2; ++mt)
#pragma unroll
    for (int cf = 0; cf < 8; ++cf) o[mt][cf] = (f32x4){0.f, 0.f, 0.f, 0.f};
  float lacc[2][4] = {{0.f, 0.f, 0.f, 0.f}, {0.f, 0.f, 0.f, 0.f}};

  for (int stp = 0; stp < 5; ++stp) {
    const int jj = jp * 640 + stp * 128;

    f32x4 s[2][8];
#pragma unroll
    for (int mt = 0; mt < 2; ++mt)
#pragma unroll
      for (int nf = 0; nf < 8; ++nf) s[mt][nf] = (f32x4){0.f, 0.f, 0.f, 0.f};

    // ---- score: S = L . R^T over K halves of 128
#pragma unroll
    for (int h = 0; h < KD / 128; ++h) {
      __syncthreads();                           // prior Rs readers done
#pragma unroll
      for (int cc = 0; cc < 8; ++cc) {
        const int jr = w * 32 + cc * 4 + (lane >> 4);
        const int cp = lane & 15;
        const int ch = (cp & ~7) | ((cp ^ jr) & 7);
        gload_lds16(Rt + (size_t)(jj + jr) * KD + h * 128 + ch * 8,
                    Rs + ((w * 8 + cc) << 9));
      }
      __syncthreads();                           // stage complete (vmcnt drain)

      bf16x8 ah[2][4];
      if constexpr (KD == 256) {
#pragma unroll
        for (int mt = 0; mt < 2; ++mt)
#pragma unroll
          for (int l = 0; l < 4; ++l)
            ah[mt][l] = *(const bf16x8*)(Lt + (size_t)(i0w + mt * 16 + jl) * KD + h * 128 + l * 32 + q * 8);
      } else {
#pragma unroll
        for (int mt = 0; mt < 2; ++mt)
#pragma unroll
          for (int l = 0; l < 4; ++l)
            ah[mt][l] = afr128[mt][l];
      }
#pragma unroll
      for (int nf = 0; nf < 8; ++nf) {
        const int row = nf * 16 + jl;
#pragma unroll
        for (int l = 0; l < 4; ++l) {
          const int ch = (l * 4 + q) ^ (jl & 7); // un-swizzle
          bf16x8 b = *(const bf16x8*)(Rs + row * 128 + ch * 8);
          s[0][nf] = MFMA(ah[0][l], b, s[0][nf]);
          s[1][nf] = MFMA(ah[1][l], b, s[1][nf]);
        }
      }
    }

    // ---- P = exp(S); accumulate rowsums in registers
#pragma unroll
    for (int mt = 0; mt < 2; ++mt)
#pragma unroll
      for (int nf = 0; nf < 8; ++nf)
#pragma unroll
        for (int r = 0; r < 4; ++r) {
          float p = __expf(s[mt][nf][r]);
          s[mt][nf][r] = p;
          lacc[mt][r] += p;
        }

    __syncthreads();                             // score Rs reads done
    // ---- transpose P C-frags -> T buffers (aliasing Rs), chunk-XOR swizzle
#pragma unroll
    for (int nf = 0; nf < 8; ++nf)
#pragma unroll
      for (int r = 0; r < 4; ++r) {
        const int row = q * 4 + r;
        const int chs = (nf * 2 + (jl >> 3)) ^ (row & 7);
        T0[row * 128 + chs * 8 + (jl & 7)] = f2b(s[0][nf][r]);
        T1[row * 128 + chs * 8 + (jl & 7)] = f2b(s[1][nf][r]);
      }
    __syncthreads();                             // T visible

    // ---- PV: O += P . V^T, V B-frags direct from global (L1/L2-resident)
#pragma unroll
    for (int ks2 = 0; ks2 < 4; ++ks2) {
      const int kcs = ((ks2 * 4 + q) ^ (jl & 7)) * 8;
      bf16x8 pa0 = *(const bf16x8*)(T0 + jl * 128 + kcs);
      bf16x8 pa1 = *(const bf16x8*)(T1 + jl * 128 + kcs);
#pragma unroll
      for (int cf = 0; cf < 8; ++cf) {
        bf16x8 bv = *(const bf16x8*)(Vm + (size_t)(cf * 16 + jl) * HW + jj + ks2 * 32 + q * 8);
        o[0][cf] = MFMA(pa0, bv, o[0][cf]);
        o[1][cf] = MFMA(pa1, bv, o[1][cf]);
      }
    }
  }

  // ---- epilogue: l rowsum reduce + atomics, O atomics (L2-resident)
#pragma unroll
  for (int mt = 0; mt < 2; ++mt) {
    float rs[4] = {lacc[mt][0], lacc[mt][1], lacc[mt][2], lacc[mt][3]};
#pragma unroll
    for (int d = 1; d < 16; d <<= 1)
#pragma unroll
      for (int r = 0; r < 4; ++r) rs[r] += __shfl_xor(rs[r], d);
    if (jl == 0) {
#pragma unroll
      for (int r = 0; r < 4; ++r)
        atomicAdd(&lv[i0w + mt * 16 + q * 4 + r], rs[r]);
    }
  }
#pragma unroll
  for (int mt = 0; mt < 2; ++mt) {
    const int ib = i0w + mt * 16 + q * 4;
#pragma unroll
    for (int cf = 0; cf < 8; ++cf) {
      const int c = cf * 16 + jl;
#pragma unroll
      for (int r = 0; r < 4; ++r)
        atomicAdd(&O[(size_t)(ib + r) * 128 + c], o[mt][cf][r]);
    }
  }
}

// grid <<<1000, 256>>>: bid<500 head1 (KD=256), else head2 (KD=128).
// LDS 32KB; launch_bounds(256,2) -> natural VGPR alloc (no forced spill);
// at ~128 VGPR the limiter is VGPR: 4 blocks/CU = 16 waves/CU.
__global__ __launch_bounds__(256, 2) void fused_attn(
    const u16* __restrict__ LT, const u16* __restrict__ RT, const u16* __restrict__ Vv,
    const u16* __restrict__ pT, const u16* __restrict__ efT, const u16* __restrict__ efc,
    float* __restrict__ Obuf, float* __restrict__ lbuf)
{
  __shared__ __align__(1024) u16 Rs[128 * 128];
  const int bid = blockIdx.x;
  if (bid < 500)
    attn_body<256>(LT, RT, Vv, Obuf, lbuf, bid, Rs);
  else
    attn_body<128>(pT, efT, efc, Obuf + (size_t)HW * 128, lbuf + HW, bid - 500, Rs);
}

// ---------------------------------------------------------------------------
// final_k: out[d][i] = x[d][i] + silu(o1.w2b + b2e) + silu(o2.w3b + b3e),
// o?[i][c] = O[h][i][c] / l[h][i], built as bf16 A-frags on the fly.
// grid dim3(100, 2), 256 thr.
// ---------------------------------------------------------------------------
__global__ __launch_bounds__(256) void final_k(
    const float* __restrict__ Obuf,    // [2][HW][128]
    const float* __restrict__ lbuf,    // [2][HW]
    const u16* __restrict__ w2b, const float* __restrict__ b2e,
    const u16* __restrict__ w3b, const float* __restrict__ b3e,
    const float* __restrict__ x, float* __restrict__ outp)
{
  const int t = threadIdx.x, w = t >> 6, lane = t & 63, jl = lane & 15, q = lane >> 4;
  const int i0 = blockIdx.x * 64 + w * 16;
  const int nc = blockIdx.y;
  const int row = i0 + jl;

  const float inv1 = 1.0f / lbuf[row];
  const float inv2 = 1.0f / lbuf[HW + row];
  const float* O1 = Obuf + (size_t)row * 128;
  const float* O2 = Obuf + (size_t)(HW + row) * 128;

  f32x4 a1[8], a2[8];
#pragma unroll
  for (int nf = 0; nf < 8; ++nf) {
    a1[nf] = (f32x4){0.f, 0.f, 0.f, 0.f};
    a2[nf] = (f32x4){0.f, 0.f, 0.f, 0.f};
  }
#pragma unroll
  for (int ks = 0; ks < 4; ++ks) {
    f32x4 s1a = *(const f32x4*)(O1 + ks * 32 + q * 8);
    f32x4 s1b = *(const f32x4*)(O1 + ks * 32 + q * 8 + 4);
    f32x4 s2a = *(const f32x4*)(O2 + ks * 32 + q * 8);
    f32x4 s2b = *(const f32x4*)(O2 + ks * 32 + q * 8 + 4);
    bf16x8 fa1 = pack8(s1a, s1b, inv1);
    bf16x8 fa2 = pack8(s2a, s2b, inv2);
#pragma unroll
    for (int nf = 0; nf < 8; ++nf) {
      bf16x8 b2f = *(const bf16x8*)(w2b + (size_t)(nc * 128 + nf * 16 + jl) * 128 + ks * 32 + q * 8);
      bf16x8 b3f = *(const bf16x8*)(w3b + (size_t)(nc * 128 + nf * 16 + jl) * 128 + ks * 32 + q * 8);
      a1[nf] = MFMA(fa1, b2f, a1[nf]);
      a2[nf] = MFMA(fa2, b3f, a2[nf]);
    }
  }
#pragma unroll
  for (int nf = 0; nf < 8; ++nf) {
    const int d = nc * 128 + nf * 16 + jl;
    const float bb2 = b2e[d], bb3 = b3e[d];
    const size_t base = (size_t)d * HW + i0 + q * 4;
    f32x4 xv = *(const f32x4*)(x + base);
    f32x4 rv;
#pragma unroll
    for (int r = 0; r < 4; ++r)
      rv[r] = xv[r] + silu_f(a1[nf][r] + bb2) + silu_f(a2[nf][r] + bb3);
    *(f32x4*)(outp + base) = rv;
  }
}

// ---------------------------------------------------------------------------
extern "C" void kernel_launch(void* const* d_in, const int* in_sizes, int n_in,
                              void* d_out, int out_size, void* d_ws, size_t ws_size,
                              hipStream_t stream)
{
  (void)in_sizes; (void)n_in; (void)out_size; (void)ws_size;
  const float* x   = (const float*)d_in[0];
  const float* w1  = (const float*)d_in[1];
  const float* g1  = (const float*)d_in[2];
  const float* b1  = (const float*)d_in[3];
  const float* m1  = (const float*)d_in[4];
  const float* v1  = (const float*)d_in[5];
  const float* w2  = (const float*)d_in[6];
  const float* g2  = (const float*)d_in[7];
  const float* b2  = (const float*)d_in[8];
  const float* m2  = (const float*)d_in[9];
  const float* v2  = (const float*)d_in[10];
  const float* w3  = (const float*)d_in[11];
  const float* g3  = (const float*)d_in[12];
  const float* b3  = (const float*)d_in[13];
  const float* m3  = (const float*)d_in[14];
  const float* v3  = (const float*)d_in[15];
  const float* wq  = (const float*)d_in[16];
  const float* bq  = (const float*)d_in[17];
  const float* wk  = (const float*)d_in[18];
  const float* bk  = (const float*)d_in[19];
  const float* wv  = (const float*)d_in[20];
  const float* bv  = (const float*)d_in[21];
  const float* wp  = (const float*)d_in[22];
  const float* bp  = (const float*)d_in[23];
  const float* rel_h = (const float*)d_in[24];
  const float* rel_w = (const float*)d_in[25];
  const float* ef_h  = (const float*)d_in[26];
  const float* ef_w  = (const float*)d_in[27];
  float* outp = (float*)d_out;

  char* ws = (char*)d_ws;
  size_t off = 0;
  auto alloc = [&](size_t bytes) -> void* {
    void* p = ws + off;
    off += (bytes + 511) & ~(size_t)511;
    return p;
  };
  u16* LT    = (u16*)alloc((size_t)HW * 256 * 2);
  u16* RT    = (u16*)alloc((size_t)HW * 256 * 2);
  u16* pT    = (u16*)alloc((size_t)HW * 128 * 2);
  u16* efT   = (u16*)alloc((size_t)HW * 128 * 2);
  u16* efc   = (u16*)alloc((size_t)HW * 128 * 2);
  u16* Vv    = (u16*)alloc((size_t)HW * 128 * 2);
  float* Obuf = (float*)alloc((size_t)2 * HW * 128 * 4);    // 6.55 MB
  float* lbuf = (float*)alloc((size_t)2 * HW * 4);
  u16* w1b   = (u16*)alloc(128 * 256 * 2);
  float* b1e = (float*)alloc(128 * 4);
  u16* Wcat  = (u16*)alloc(512 * 128 * 2);
  float* bcat = (float*)alloc(512 * 4);
  u16* w2b   = (u16*)alloc(256 * 128 * 2);
  float* b2e = (float*)alloc(256 * 4);
  u16* w3b   = (u16*)alloc(256 * 128 * 2);
  float* b3e = (float*)alloc(256 * 4);

  prep_all<<<176, 256, 0, stream>>>(rel_h, rel_w, ef_h, ef_w,
                                    w1, g1, b1, m1, v1, w2, g2, b2, m2, v2,
                                    w3, g3, b3, m3, v3, wq, bq, wk, bk, wv, bv, wp, bp,
                                    LT, efT, efc,
                                    w1b, b1e, Wcat, bcat, w2b, b2e, w3b, b3e,
                                    Obuf, lbuf);
  front_k<<<200, 128, 0, stream>>>(x, w1b, b1e, Wcat, bcat, LT, RT, Vv, pT);
  fused_attn<<<1000, 256, 0, stream>>>(LT, RT, Vv, pT, efT, efc, Obuf, lbuf);
  final_k<<<dim3(100, 2), 256, 0, stream>>>(Obuf, lbuf, w2b, b2e, w3b, b3e, x, outp);
}

// Round 4
// 310.358 us; speedup vs baseline: 1.6258x; 1.0829x over previous
//
#include <hip/hip_runtime.h>

// ============================================================================
// ExtraMHSA pipeline for MI355X (gfx950).  R9: swapped-score + stage-ahead.
//
//   prep_all   : pos embeds, BN-fold weights->bf16, zero O/l
//   front_k    : x ->(regs) x1=silu(conv1) ->(LDS) q,k,v,p -> LT/RT/Vv/pT
//   fused_attn : flash-style, P never to HBM.  R9 changes vs R8:
//     - Score computes S^T via MFMA(R_frag, L_frag) (identical per-lane A/B
//       layouts -> same loads, swapped args).  Thread then holds P with
//       row i lane-local: transpose to PV-A-frag layout is 16 ds_write_b64
//       (vs 64 b16) into a PER-WAVE T buffer -> wave-local lgkmcnt fence,
//       no block barriers around the handoff.
//     - T is its own 32KB (not aliased in Rs): LDS 64KB.  Occupancy is
//       register-capped at 2 blocks/CU anyway (VGPR 128 arch + ~128 AGPR
//       accumulators = full 256/wave envelope; R8 proved LDS 66->32KB left
//       occupancy at 21%), so the extra LDS is free and removes 2 barriers.
//     - Stage-ahead: next R-tile's global_load_lds issued right after the
//       post-score barrier, so the vmcnt drain overlaps exp+transpose+PV.
//       Barriers/step: 4 (KD=256) / 2 (KD=128), was 6/4.
//     - L A-frags fully resident per block (64 VGPR for KD=256, R6-style);
//       fits the 256-reg envelope, removes per-h reloads behind barriers.
//   final_k    : out = x + silu(bn(conv2(O1/l1))) + silu(bn(conv3(O2/l2)))
// ============================================================================

typedef unsigned short u16;
typedef __attribute__((ext_vector_type(8))) short bf16x8;   // 8 bf16 = 4 VGPRs
typedef __attribute__((ext_vector_type(4))) float f32x4;    // MFMA C/D frag
typedef __attribute__((ext_vector_type(4))) unsigned int u32x4;

#define HW 6400
#define BN_EPS 1e-5f

__device__ __forceinline__ u16 f2b(float f) {       // fp32 -> bf16 RNE
  unsigned u = __float_as_uint(f);
  u += 0x7fffu + ((u >> 16) & 1u);
  return (u16)(u >> 16);
}
__device__ __forceinline__ unsigned pack2(float a, float b) {
  return (unsigned)f2b(a) | ((unsigned)f2b(b) << 16);
}
__device__ __forceinline__ f32x4 MFMA(bf16x8 a, bf16x8 b, f32x4 c) {
  return __builtin_amdgcn_mfma_f32_16x16x32_bf16(a, b, c, 0, 0, 0);
}
__device__ __forceinline__ float silu_f(float y) {
  return y / (1.0f + __expf(-y));
}
__device__ __forceinline__ bf16x8 pack8(f32x4 lo, f32x4 hi, float sc) {
  union { bf16x8 v; uint4 u; } r;
  r.u.x = pack2(lo[0] * sc, lo[1] * sc);
  r.u.y = pack2(lo[2] * sc, lo[3] * sc);
  r.u.z = pack2(hi[0] * sc, hi[1] * sc);
  r.u.w = pack2(hi[2] * sc, hi[3] * sc);
  return r.v;
}
// async global->LDS, 16B per lane; dst is wave-uniform base (HW adds lane*16).
__device__ __forceinline__ void gload_lds16(const u16* src, u16* dst) {
  __builtin_amdgcn_global_load_lds(
      (const __attribute__((address_space(1))) void*)src,
      (__attribute__((address_space(3))) void*)dst, 16, 0, 0);
}
// Wave-local LDS write->read handoff (cross-lane within wave): compiler
// fence + hw drain (R5 lesson: alias analysis misses cross-lane deps).
__device__ __forceinline__ void lds_fence() {
  __builtin_amdgcn_sched_barrier(0);
  asm volatile("s_waitcnt lgkmcnt(0)" ::: "memory");
  __builtin_amdgcn_sched_barrier(0);
}

// ---------------------------------------------------------------------------
// prep_all: [0,80) pos embeds; [80,144) weight BN-fold; [144,176) zero O/l.
// ---------------------------------------------------------------------------
__global__ void prep_all(
    const float* __restrict__ rel_h, const float* __restrict__ rel_w,
    const float* __restrict__ ef_h, const float* __restrict__ ef_w,
    const float* __restrict__ w1, const float* __restrict__ g1, const float* __restrict__ b1,
    const float* __restrict__ m1, const float* __restrict__ v1,
    const float* __restrict__ w2, const float* __restrict__ g2, const float* __restrict__ b2,
    const float* __restrict__ m2, const float* __restrict__ v2,
    const float* __restrict__ w3, const float* __restrict__ g3, const float* __restrict__ b3,
    const float* __restrict__ m3, const float* __restrict__ v3,
    const float* __restrict__ wq, const float* __restrict__ bq,
    const float* __restrict__ wk, const float* __restrict__ bk,
    const float* __restrict__ wv, const float* __restrict__ bv,
    const float* __restrict__ wp, const float* __restrict__ bp,
    u16* __restrict__ LT, u16* __restrict__ efT, u16* __restrict__ efc,
    u16* __restrict__ w1b, float* __restrict__ b1e,
    u16* __restrict__ Wcat, float* __restrict__ bcat,
    u16* __restrict__ w2b, float* __restrict__ b2e,
    u16* __restrict__ w3b, float* __restrict__ b3e,
    float* __restrict__ Obuf, float* __restrict__ lbuf)
{
  const int b = blockIdx.x;
  const int t = threadIdx.x;
  if (b < 80) {
    const int h = b;
    const int c0 = (t & 63) * 2;
    const float rh0 = rel_h[c0 * 80 + h], rh1 = rel_h[(c0 + 1) * 80 + h];
    const float eh0 = ef_h[c0 * 80 + h], eh1 = ef_h[(c0 + 1) * 80 + h];
    for (int wcol = (t >> 6); wcol < 80; wcol += 4) {
      const int i = h * 80 + wcol;
      float rw0 = rel_w[c0 * 80 + wcol], rw1 = rel_w[(c0 + 1) * 80 + wcol];
      float ew0 = ef_w[c0 * 80 + wcol], ew1 = ef_w[(c0 + 1) * 80 + wcol];
      *(unsigned*)&LT[(size_t)i * 256 + 128 + c0] = pack2(rh0 + rw0, rh1 + rw1);
      float e0 = eh0 + ew0, e1 = eh1 + ew1;
      *(unsigned*)&efT[(size_t)i * 128 + c0] = pack2(e0, e1);
      efc[(size_t)c0 * HW + i] = f2b(e0);
      efc[(size_t)(c0 + 1) * HW + i] = f2b(e1);
    }
  } else if (b < 144) {
    const int tid = (b - 80) * 256 + t;
    const int stride = 64 * 256;
    for (int idx = tid; idx < 128 * 256; idx += stride) {
      int o = idx >> 8;
      float s = g1[o] * rsqrtf(v1[o] + BN_EPS);
      w1b[idx] = f2b(w1[idx] * s);
    }
    for (int idx = tid; idx < 128; idx += stride) {
      float s = g1[idx] * rsqrtf(v1[idx] + BN_EPS);
      b1e[idx] = b1[idx] - m1[idx] * s;
    }
    for (int idx = tid; idx < 4 * 128 * 128; idx += stride) {
      int which = idx >> 14, r = idx & 16383;
      const float* src = which == 0 ? wq : which == 1 ? wk : which == 2 ? wv : wp;
      Wcat[idx] = f2b(src[r]);
    }
    for (int idx = tid; idx < 512; idx += stride) {
      int which = idx >> 7, r = idx & 127;
      const float* src = which == 0 ? bq : which == 1 ? bk : which == 2 ? bv : bp;
      bcat[idx] = src[r];
    }
    for (int idx = tid; idx < 256 * 128; idx += stride) {
      int o = idx >> 7;
      float s2 = g2[o] * rsqrtf(v2[o] + BN_EPS);
      w2b[idx] = f2b(w2[idx] * s2);
      float s3 = g3[o] * rsqrtf(v3[o] + BN_EPS);
      w3b[idx] = f2b(w3[idx] * s3);
    }
    for (int idx = tid; idx < 256; idx += stride) {
      float s2 = g2[idx] * rsqrtf(v2[idx] + BN_EPS);
      b2e[idx] = b2[idx] - m2[idx] * s2;
      float s3 = g3[idx] * rsqrtf(v3[idx] + BN_EPS);
      b3e[idx] = b3[idx] - m3[idx] * s3;
    }
  } else {
    const int tid = (b - 144) * 256 + t;
    const int stride = 32 * 256;
    f32x4 z = {0.f, 0.f, 0.f, 0.f};
    for (int idx = tid; idx < 2 * HW * 128 / 4; idx += stride)
      ((f32x4*)Obuf)[idx] = z;
    for (int idx = tid; idx < 2 * HW / 4; idx += stride)
      ((f32x4*)lbuf)[idx] = z;
  }
}

// ---------------------------------------------------------------------------
// front_k: fused  x -> x1=silu(bn(conv1(x))) -> {q,k,v,p} -> LT/RT/Vv/pT.
// grid <<<200, 128>>>: 2 waves x 16 i-rows.
// ---------------------------------------------------------------------------
__global__ __launch_bounds__(128) void front_k(
    const float* __restrict__ x,
    const u16* __restrict__ w1b, const float* __restrict__ b1e,
    const u16* __restrict__ Wcat, const float* __restrict__ bcat,
    u16* __restrict__ LT, u16* __restrict__ RT, u16* __restrict__ Vv,
    u16* __restrict__ pT)
{
  __shared__ __align__(16) u16 tr[2][16][136];
  const int t = threadIdx.x, w = t >> 6, lane = t & 63, jl = lane & 15, q = lane >> 4;
  const int i0 = blockIdx.x * 32 + w * 16;

  bf16x8 afr[8];
#pragma unroll
  for (int ks = 0; ks < 8; ++ks) {
    union { bf16x8 v; u16 e[8]; } fa;
#pragma unroll
    for (int e = 0; e < 8; ++e)
      fa.e[e] = f2b(x[(size_t)(ks * 32 + q * 8 + e) * HW + i0 + jl]);
    afr[ks] = fa.v;
  }
  f32x4 acc[8];
#pragma unroll
  for (int nf = 0; nf < 8; ++nf) acc[nf] = (f32x4){0.f, 0.f, 0.f, 0.f};
#pragma unroll
  for (int ks = 0; ks < 8; ++ks)
#pragma unroll
    for (int nf = 0; nf < 8; ++nf) {
      bf16x8 b = *(const bf16x8*)(w1b + (size_t)(nf * 16 + jl) * 256 + ks * 32 + q * 8);
      acc[nf] = MFMA(afr[ks], b, acc[nf]);
    }
#pragma unroll
  for (int nf = 0; nf < 8; ++nf) {
    const int c = nf * 16 + jl;
    const float bias = b1e[c];
#pragma unroll
    for (int r = 0; r < 4; ++r)
      tr[w][q * 4 + r][c] = f2b(silu_f(acc[nf][r] + bias));
  }
  __syncthreads();
  bf16x8 xa[4];
#pragma unroll
  for (int ks = 0; ks < 4; ++ks)
    xa[ks] = *(const bf16x8*)&tr[w][jl][ks * 32 + q * 8];

#pragma unroll
  for (int nc = 0; nc < 4; ++nc) {
    f32x4 a2[8];
#pragma unroll
    for (int nf = 0; nf < 8; ++nf) a2[nf] = (f32x4){0.f, 0.f, 0.f, 0.f};
#pragma unroll
    for (int ks = 0; ks < 4; ++ks)
#pragma unroll
      for (int nf = 0; nf < 8; ++nf) {
        bf16x8 b = *(const bf16x8*)(Wcat + (size_t)(nc * 128 + nf * 16 + jl) * 128 + ks * 32 + q * 8);
        a2[nf] = MFMA(xa[ks], b, a2[nf]);
      }
    if (nc == 2) {
#pragma unroll
      for (int nf = 0; nf < 8; ++nf) {
        const int c = nf * 16 + jl;
        const float bias = bcat[256 + c];
        uint2 pk;
        pk.x = pack2(a2[nf][0] + bias, a2[nf][1] + bias);
        pk.y = pack2(a2[nf][2] + bias, a2[nf][3] + bias);
        *(uint2*)(Vv + (size_t)c * HW + i0 + q * 4) = pk;
      }
    } else {
      __syncthreads();
#pragma unroll
      for (int nf = 0; nf < 8; ++nf) {
        const int c = nf * 16 + jl;
        const float bias = bcat[nc * 128 + c];
#pragma unroll
        for (int r = 0; r < 4; ++r)
          tr[w][q * 4 + r][c] = f2b(a2[nf][r] + bias);
      }
      __syncthreads();
#pragma unroll
      for (int r = 0; r < 16; ++r) {
        unsigned val = *(const unsigned*)&tr[w][r][lane * 2];
        const size_t row = (size_t)(i0 + r);
        if (nc == 0) {
          *(unsigned*)(LT + row * 256 + lane * 2) = val;
          *(unsigned*)(RT + row * 256 + 128 + lane * 2) = val;
        } else if (nc == 1) {
          *(unsigned*)(RT + row * 256 + lane * 2) = val;
        } else {
          *(unsigned*)(pT + row * 128 + lane * 2) = val;
        }
      }
    }
  }
}

// ---------------------------------------------------------------------------
// fused_attn body.  LDS: Rs 32KB (R-tile, XOR-8 chunk swizzle via
// global_load_lds pre-swizzled source) + per-wave T [2 it][16 i][128 j]
// (8KB/wave, chunk-XOR swizzle c^=(jl&7)<<2).
//
// Score computes S^T = MFMA(R_frag, L_frag): thread (jl,q) holds, for
// m-tile nf / n-tile it:  S[i0w + it*16 + jl][jj + nf*16 + q*4 + r].
// Row i is lane-local -> transpose = 2x8 ds_write_b64, wave-local fence,
// PV A-frags read back as b128.
// ---------------------------------------------------------------------------
template <int KD>
__device__ __forceinline__ void attn_body(
    const u16* __restrict__ Lt,     // [HW][KD]
    const u16* __restrict__ Rt,     // [HW][KD]
    const u16* __restrict__ Vm,     // [128][HW]
    float* __restrict__ O,          // [HW][128]
    float* __restrict__ lv,         // [HW]
    int bid, u16* __restrict__ Rs, u16* __restrict__ Tw)
{
  const int t = threadIdx.x, lane = t & 63, w = t >> 6, jl = lane & 15, q = lane >> 4;
  const int it = bid / 10, jp = bid % 10;
  const int i0w = it * 128 + w * 32;
  constexpr int H = KD / 128;

  // L A-frags fully resident (B-operand of swapped score; same per-lane
  // layout as A).  KD=256: 64 VGPR, KD=128: 32.
  bf16x8 afr[2][H * 4];
#pragma unroll
  for (int mt = 0; mt < 2; ++mt)
#pragma unroll
    for (int l = 0; l < H * 4; ++l)
      afr[mt][l] = *(const bf16x8*)(Lt + (size_t)(i0w + mt * 16 + jl) * KD + l * 32 + q * 8);

  f32x4 o[2][8];
#pragma unroll
  for (int mt = 0; mt < 2; ++mt)
#pragma unroll
    for (int cf = 0; cf < 8; ++cf) o[mt][cf] = (f32x4){0.f, 0.f, 0.f, 0.f};
  float lacc[2] = {0.f, 0.f};

  // stage one 128j x 128k half-tile: 8 gload_lds per wave (XOR-8 swizzle
  // on the per-lane global source, linear LDS dest)
  auto stage = [&](int jjs, int h) {
#pragma unroll
    for (int cc = 0; cc < 8; ++cc) {
      const int jr = w * 32 + cc * 4 + (lane >> 4);
      const int cp = lane & 15;
      const int ch = (cp & ~7) | ((cp ^ jr) & 7);
      gload_lds16(Rt + (size_t)(jjs + jr) * KD + h * 128 + ch * 8,
                  Rs + ((w * 8 + cc) << 9));
    }
  };

  stage(jp * 640, 0);                            // prologue

  for (int stp = 0; stp < 5; ++stp) {
    const int jj = jp * 640 + stp * 128;

    f32x4 s[8][2];
#pragma unroll
    for (int nf = 0; nf < 8; ++nf)
#pragma unroll
      for (int mt = 0; mt < 2; ++mt) s[nf][mt] = (f32x4){0.f, 0.f, 0.f, 0.f};

    // ---- score: S^T += R . L^T over K halves of 128
#pragma unroll
    for (int h = 0; h < H; ++h) {
      __syncthreads();                           // staged data visible
#pragma unroll
      for (int nf = 0; nf < 8; ++nf) {
        const int row = nf * 16 + jl;
#pragma unroll
        for (int l = 0; l < 4; ++l) {
          const int ch = (l * 4 + q) ^ (jl & 7); // un-swizzle
          bf16x8 b = *(const bf16x8*)(Rs + row * 128 + ch * 8);
          s[nf][0] = MFMA(b, afr[0][h * 4 + l], s[nf][0]);
          s[nf][1] = MFMA(b, afr[1][h * 4 + l], s[nf][1]);
        }
      }
      __syncthreads();                           // all waves' Rs reads done
      // stage-ahead: overwrite Rs now; drain overlaps exp/transpose/PV
      if (h < H - 1)      stage(jj, h + 1);
      else if (stp < 4)   stage(jj + 128, 0);
    }

    // ---- P = exp(S); per-thread rowsum partials (full row = reduce over q)
#pragma unroll
    for (int nf = 0; nf < 8; ++nf)
#pragma unroll
      for (int mt = 0; mt < 2; ++mt)
#pragma unroll
        for (int r = 0; r < 4; ++r) {
          float p = __expf(s[nf][mt][r]);
          s[nf][mt][r] = p;
          lacc[mt] += p;
        }

    // ---- wave-local transpose: thread owns row i=jl, 4 consecutive j per
    // (nf): one b64 write, chunk-XOR swizzle
#pragma unroll
    for (int mt = 0; mt < 2; ++mt)
#pragma unroll
      for (int nf = 0; nf < 8; ++nf) {
        const int cs = (nf * 4 + q) ^ ((jl & 7) << 2);
        uint2 pk;
        pk.x = pack2(s[nf][mt][0], s[nf][mt][1]);
        pk.y = pack2(s[nf][mt][2], s[nf][mt][3]);
        *(uint2*)(Tw + (mt * 16 + jl) * 128 + cs * 4) = pk;
      }
    lds_fence();                                 // wave-local handoff

    // ---- PV: O += P . V^T, V B-frags direct from global (L1/L2-resident)
#pragma unroll
    for (int ks2 = 0; ks2 < 4; ++ks2) {
      const int cb = (ks2 * 8 + q * 2) ^ ((jl & 7) << 2);
      bf16x8 pa0 = *(const bf16x8*)(Tw + jl * 128 + cb * 4);
      bf16x8 pa1 = *(const bf16x8*)(Tw + (16 + jl) * 128 + cb * 4);
#pragma unroll
      for (int cf = 0; cf < 8; ++cf) {
        bf16x8 bv = *(const bf16x8*)(Vm + (size_t)(cf * 16 + jl) * HW + jj + ks2 * 32 + q * 8);
        o[0][cf] = MFMA(pa0, bv, o[0][cf]);
        o[1][cf] = MFMA(pa1, bv, o[1][cf]);
      }
    }
  }

  // ---- epilogue: l rowsum reduce over q-lanes + atomics, O atomics
#pragma unroll
  for (int mt = 0; mt < 2; ++mt) {
    float rsum = lacc[mt];
    rsum += __shfl_xor(rsum, 16);
    rsum += __shfl_xor(rsum, 32);
    if (lane < 16)
      atomicAdd(&lv[i0w + mt * 16 + jl], rsum);
  }
#pragma unroll
  for (int mt = 0; mt < 2; ++mt) {
    const int ib = i0w + mt * 16 + q * 4;
#pragma unroll
    for (int cf = 0; cf < 8; ++cf) {
      const int c = cf * 16 + jl;
#pragma unroll
      for (int r = 0; r < 4; ++r)
        atomicAdd(&O[(size_t)(ib + r) * 128 + c], o[mt][cf][r]);
    }
  }
}

// grid <<<1000, 256>>>: bid<500 head1 (KD=256), else head2 (KD=128).
// LDS 64KB (Rs 32K + T 32K); occupancy reg-capped at 2 blocks/CU (VGPR+AGPR
// ~256/wave), so 64KB LDS costs nothing.
__global__ __launch_bounds__(256, 2) void fused_attn(
    const u16* __restrict__ LT, const u16* __restrict__ RT, const u16* __restrict__ Vv,
    const u16* __restrict__ pT, const u16* __restrict__ efT, const u16* __restrict__ efc,
    float* __restrict__ Obuf, float* __restrict__ lbuf)
{
  __shared__ __align__(1024) u16 Rs[128 * 128];
  __shared__ __align__(1024) u16 Ts[4][32 * 128];
  const int w = threadIdx.x >> 6;
  const int bid = blockIdx.x;
  if (bid < 500)
    attn_body<256>(LT, RT, Vv, Obuf, lbuf, bid, Rs, Ts[w]);
  else
    attn_body<128>(pT, efT, efc, Obuf + (size_t)HW * 128, lbuf + HW, bid - 500,
                   Rs, Ts[w]);
}

// ---------------------------------------------------------------------------
// final_k: out[d][i] = x[d][i] + silu(o1.w2b + b2e) + silu(o2.w3b + b3e),
// o?[i][c] = O[h][i][c] / l[h][i], built as bf16 A-frags on the fly.
// grid dim3(100, 2), 256 thr.
// ---------------------------------------------------------------------------
__global__ __launch_bounds__(256) void final_k(
    const float* __restrict__ Obuf,    // [2][HW][128]
    const float* __restrict__ lbuf,    // [2][HW]
    const u16* __restrict__ w2b, const float* __restrict__ b2e,
    const u16* __restrict__ w3b, const float* __restrict__ b3e,
    const float* __restrict__ x, float* __restrict__ outp)
{
  const int t = threadIdx.x, w = t >> 6, lane = t & 63, jl = lane & 15, q = lane >> 4;
  const int i0 = blockIdx.x * 64 + w * 16;
  const int nc = blockIdx.y;
  const int row = i0 + jl;

  const float inv1 = 1.0f / lbuf[row];
  const float inv2 = 1.0f / lbuf[HW + row];
  const float* O1 = Obuf + (size_t)row * 128;
  const float* O2 = Obuf + (size_t)(HW + row) * 128;

  f32x4 a1[8], a2[8];
#pragma unroll
  for (int nf = 0; nf < 8; ++nf) {
    a1[nf] = (f32x4){0.f, 0.f, 0.f, 0.f};
    a2[nf] = (f32x4){0.f, 0.f, 0.f, 0.f};
  }
#pragma unroll
  for (int ks = 0; ks < 4; ++ks) {
    f32x4 s1a = *(const f32x4*)(O1 + ks * 32 + q * 8);
    f32x4 s1b = *(const f32x4*)(O1 + ks * 32 + q * 8 + 4);
    f32x4 s2a = *(const f32x4*)(O2 + ks * 32 + q * 8);
    f32x4 s2b = *(const f32x4*)(O2 + ks * 32 + q * 8 + 4);
    bf16x8 fa1 = pack8(s1a, s1b, inv1);
    bf16x8 fa2 = pack8(s2a, s2b, inv2);
#pragma unroll
    for (int nf = 0; nf < 8; ++nf) {
      bf16x8 b2f = *(const bf16x8*)(w2b + (size_t)(nc * 128 + nf * 16 + jl) * 128 + ks * 32 + q * 8);
      bf16x8 b3f = *(const bf16x8*)(w3b + (size_t)(nc * 128 + nf * 16 + jl) * 128 + ks * 32 + q * 8);
      a1[nf] = MFMA(fa1, b2f, a1[nf]);
      a2[nf] = MFMA(fa2, b3f, a2[nf]);
    }
  }
#pragma unroll
  for (int nf = 0; nf < 8; ++nf) {
    const int d = nc * 128 + nf * 16 + jl;
    const float bb2 = b2e[d], bb3 = b3e[d];
    const size_t base = (size_t)d * HW + i0 + q * 4;
    f32x4 xv = *(const f32x4*)(x + base);
    f32x4 rv;
#pragma unroll
    for (int r = 0; r < 4; ++r)
      rv[r] = xv[r] + silu_f(a1[nf][r] + bb2) + silu_f(a2[nf][r] + bb3);
    *(f32x4*)(outp + base) = rv;
  }
}

// ---------------------------------------------------------------------------
extern "C" void kernel_launch(void* const* d_in, const int* in_sizes, int n_in,
                              void* d_out, int out_size, void* d_ws, size_t ws_size,
                              hipStream_t stream)
{
  (void)in_sizes; (void)n_in; (void)out_size; (void)ws_size;
  const float* x   = (const float*)d_in[0];
  const float* w1  = (const float*)d_in[1];
  const float* g1  = (const float*)d_in[2];
  const float* b1  = (const float*)d_in[3];
  const float* m1  = (const float*)d_in[4];
  const float* v1  = (const float*)d_in[5];
  const float* w2  = (const float*)d_in[6];
  const float* g2  = (const float*)d_in[7];
  const float* b2  = (const float*)d_in[8];
  const float* m2  = (const float*)d_in[9];
  const float* v2  = (const float*)d_in[10];
  const float* w3  = (const float*)d_in[11];
  const float* g3  = (const float*)d_in[12];
  const float* b3  = (const float*)d_in[13];
  const float* m3  = (const float*)d_in[14];
  const float* v3  = (const float*)d_in[15];
  const float* wq  = (const float*)d_in[16];
  const float* bq  = (const float*)d_in[17];
  const float* wk  = (const float*)d_in[18];
  const float* bk  = (const float*)d_in[19];
  const float* wv  = (const float*)d_in[20];
  const float* bv  = (const float*)d_in[21];
  const float* wp  = (const float*)d_in[22];
  const float* bp  = (const float*)d_in[23];
  const float* rel_h = (const float*)d_in[24];
  const float* rel_w = (const float*)d_in[25];
  const float* ef_h  = (const float*)d_in[26];
  const float* ef_w  = (const float*)d_in[27];
  float* outp = (float*)d_out;

  char* ws = (char*)d_ws;
  size_t off = 0;
  auto alloc = [&](size_t bytes) -> void* {
    void* p = ws + off;
    off += (bytes + 511) & ~(size_t)511;
    return p;
  };
  u16* LT    = (u16*)alloc((size_t)HW * 256 * 2);
  u16* RT    = (u16*)alloc((size_t)HW * 256 * 2);
  u16* pT    = (u16*)alloc((size_t)HW * 128 * 2);
  u16* efT   = (u16*)alloc((size_t)HW * 128 * 2);
  u16* efc   = (u16*)alloc((size_t)HW * 128 * 2);
  u16* Vv    = (u16*)alloc((size_t)HW * 128 * 2);
  float* Obuf = (float*)alloc((size_t)2 * HW * 128 * 4);    // 6.55 MB
  float* lbuf = (float*)alloc((size_t)2 * HW * 4);
  u16* w1b   = (u16*)alloc(128 * 256 * 2);
  float* b1e = (float*)alloc(128 * 4);
  u16* Wcat  = (u16*)alloc(512 * 128 * 2);
  float* bcat = (float*)alloc(512 * 4);
  u16* w2b   = (u16*)alloc(256 * 128 * 2);
  float* b2e = (float*)alloc(256 * 4);
  u16* w3b   = (u16*)alloc(256 * 128 * 2);
  float* b3e = (float*)alloc(256 * 4);

  prep_all<<<176, 256, 0, stream>>>(rel_h, rel_w, ef_h, ef_w,
                                    w1, g1, b1, m1, v1, w2, g2, b2, m2, v2,
                                    w3, g3, b3, m3, v3, wq, bq, wk, bk, wv, bv, wp, bp,
                                    LT, efT, efc,
                                    w1b, b1e, Wcat, bcat, w2b, b2e, w3b, b3e,
                                    Obuf, lbuf);
  front_k<<<200, 128, 0, stream>>>(x, w1b, b1e, Wcat, bcat, LT, RT, Vv, pT);
  fused_attn<<<1000, 256, 0, stream>>>(LT, RT, Vv, pT, efT, efc, Obuf, lbuf);
  final_k<<<dim3(100, 2), 256, 0, stream>>>(Obuf, lbuf, w2b, b2e, w3b, b3e, x, outp);
}

// Round 5
// 256.130 us; speedup vs baseline: 1.9701x; 1.2117x over previous
//
#include <hip/hip_runtime.h>

// ============================================================================
// ExtraMHSA pipeline for MI355X (gfx950).  R10: separable head-2 + dbuf head-1
//                                               + partial-O (no O atomics).
//
//   prep_all : pos embeds, BN-fold weights->bf16, ef tables, zero l/expA/expB
//   front_k  : x ->(regs) x1=silu(conv1) ->(LDS) q,k,v,p -> LT/RT/Vv/pT
//   sep2a    : A=p^T.efh, B=p^T.efw (swapped MFMA, row-i lane-local), exp,
//              row-sums sA,sB; expA/expB stored bf16 [i][96] (16-pad of 0).
//   sep2b    : U=expA.efh^T, W=expB.efw^T (K=96), O2 = U/sA + W/sB.
//              Head-2 attention is separable: ce[i][j]=A[i,hj]+B[i,wj] =>
//              softmax factorizes; 260M MACs replace 10.5G.
//   fused_attn (head1 only): 512 thr / 8 waves / i-tile 256 / jp=10 / 5 steps.
//              Rs double-buffered 2x32KB (both K-halves staged after the
//              post-score barrier -> drain hides under exp+transpose+PV; no
//              exposed latency).  T per-wave 8KB (R9-proven layout).  LDS
//              128KB -> 1 block/CU (8 waves).  2 barriers/step.
//              O written as exclusive partials Opart[jp] (plain stores, no
//              atomics -- R5 pv_k timing suggests 8M f32 atomics ~ 40us).
//   final_k  : out = x + silu(bn(conv2((Sum_p Opart)/l1))) + silu(bn(conv3(O2)))
// ============================================================================

typedef unsigned short u16;
typedef __attribute__((ext_vector_type(8))) short bf16x8;   // 8 bf16 = 4 VGPRs
typedef __attribute__((ext_vector_type(4))) float f32x4;    // MFMA C/D frag
typedef __attribute__((ext_vector_type(4))) unsigned int u32x4;

#define HW 6400
#define BN_EPS 1e-5f

__device__ __forceinline__ u16 f2b(float f) {       // fp32 -> bf16 RNE
  unsigned u = __float_as_uint(f);
  u += 0x7fffu + ((u >> 16) & 1u);
  return (u16)(u >> 16);
}
__device__ __forceinline__ unsigned pack2(float a, float b) {
  return (unsigned)f2b(a) | ((unsigned)f2b(b) << 16);
}
__device__ __forceinline__ f32x4 MFMA(bf16x8 a, bf16x8 b, f32x4 c) {
  return __builtin_amdgcn_mfma_f32_16x16x32_bf16(a, b, c, 0, 0, 0);
}
__device__ __forceinline__ float silu_f(float y) {
  return y / (1.0f + __expf(-y));
}
__device__ __forceinline__ bf16x8 pack8(f32x4 lo, f32x4 hi, float sc) {
  union { bf16x8 v; uint4 u; } r;
  r.u.x = pack2(lo[0] * sc, lo[1] * sc);
  r.u.y = pack2(lo[2] * sc, lo[3] * sc);
  r.u.z = pack2(hi[0] * sc, hi[1] * sc);
  r.u.w = pack2(hi[2] * sc, hi[3] * sc);
  return r.v;
}
// async global->LDS, 16B per lane; dst is wave-uniform base (HW adds lane*16).
__device__ __forceinline__ void gload_lds16(const u16* src, u16* dst) {
  __builtin_amdgcn_global_load_lds(
      (const __attribute__((address_space(1))) void*)src,
      (__attribute__((address_space(3))) void*)dst, 16, 0, 0);
}
// Wave-local LDS write->read handoff (cross-lane within wave).
__device__ __forceinline__ void lds_fence() {
  __builtin_amdgcn_sched_barrier(0);
  asm volatile("s_waitcnt lgkmcnt(0)" ::: "memory");
  __builtin_amdgcn_sched_barrier(0);
}

// ---------------------------------------------------------------------------
// prep_all: [0,80) LT pos embeds; [80,144) weight BN-fold + ef tables;
//           [144,176) zero lbuf/expA/expB.
// ---------------------------------------------------------------------------
__global__ void prep_all(
    const float* __restrict__ rel_h, const float* __restrict__ rel_w,
    const float* __restrict__ ef_h, const float* __restrict__ ef_w,
    const float* __restrict__ w1, const float* __restrict__ g1, const float* __restrict__ b1,
    const float* __restrict__ m1, const float* __restrict__ v1,
    const float* __restrict__ w2, const float* __restrict__ g2, const float* __restrict__ b2,
    const float* __restrict__ m2, const float* __restrict__ v2,
    const float* __restrict__ w3, const float* __restrict__ g3, const float* __restrict__ b3,
    const float* __restrict__ m3, const float* __restrict__ v3,
    const float* __restrict__ wq, const float* __restrict__ bq,
    const float* __restrict__ wk, const float* __restrict__ bk,
    const float* __restrict__ wv, const float* __restrict__ bv,
    const float* __restrict__ wp, const float* __restrict__ bp,
    u16* __restrict__ LT,
    u16* __restrict__ w1b, float* __restrict__ b1e,
    u16* __restrict__ Wcat, float* __restrict__ bcat,
    u16* __restrict__ w2b, float* __restrict__ b2e,
    u16* __restrict__ w3b, float* __restrict__ b3e,
    u16* __restrict__ efhT, u16* __restrict__ efwT,
    u16* __restrict__ efhB, u16* __restrict__ efwB,
    u16* __restrict__ expA, u16* __restrict__ expB,
    float* __restrict__ lbuf)
{
  const int b = blockIdx.x;
  const int t = threadIdx.x;
  if (b < 80) {
    const int h = b;
    const int c0 = (t & 63) * 2;
    const float rh0 = rel_h[c0 * 80 + h], rh1 = rel_h[(c0 + 1) * 80 + h];
    for (int wcol = (t >> 6); wcol < 80; wcol += 4) {
      const int i = h * 80 + wcol;
      float rw0 = rel_w[c0 * 80 + wcol], rw1 = rel_w[(c0 + 1) * 80 + wcol];
      *(unsigned*)&LT[(size_t)i * 256 + 128 + c0] = pack2(rh0 + rw0, rh1 + rw1);
    }
  } else if (b < 144) {
    const int tid = (b - 80) * 256 + t;
    const int stride = 64 * 256;
    for (int idx = tid; idx < 128 * 256; idx += stride) {
      int o = idx >> 8;
      float s = g1[o] * rsqrtf(v1[o] + BN_EPS);
      w1b[idx] = f2b(w1[idx] * s);
    }
    for (int idx = tid; idx < 128; idx += stride) {
      float s = g1[idx] * rsqrtf(v1[idx] + BN_EPS);
      b1e[idx] = b1[idx] - m1[idx] * s;
    }
    for (int idx = tid; idx < 4 * 128 * 128; idx += stride) {
      int which = idx >> 14, r = idx & 16383;
      const float* src = which == 0 ? wq : which == 1 ? wk : which == 2 ? wv : wp;
      Wcat[idx] = f2b(src[r]);
    }
    for (int idx = tid; idx < 512; idx += stride) {
      int which = idx >> 7, r = idx & 127;
      const float* src = which == 0 ? bq : which == 1 ? bk : which == 2 ? bv : bp;
      bcat[idx] = src[r];
    }
    for (int idx = tid; idx < 256 * 128; idx += stride) {
      int o = idx >> 7;
      float s2 = g2[o] * rsqrtf(v2[o] + BN_EPS);
      w2b[idx] = f2b(w2[idx] * s2);
      float s3 = g3[o] * rsqrtf(v3[o] + BN_EPS);
      w3b[idx] = f2b(w3[idx] * s3);
    }
    for (int idx = tid; idx < 256; idx += stride) {
      float s2 = g2[idx] * rsqrtf(v2[idx] + BN_EPS);
      b2e[idx] = b2[idx] - m2[idx] * s2;
      float s3 = g3[idx] * rsqrtf(v3[idx] + BN_EPS);
      b3e[idx] = b3[idx] - m3[idx] * s3;
    }
    // ef tables: efhT/efwT [hj][c] (for sep2a B-op); efhB/efwB [c][96] padded
    for (int idx = tid; idx < 80 * 128; idx += stride) {
      int hj = idx >> 7, c = idx & 127;
      efhT[idx] = f2b(ef_h[c * 80 + hj]);
      efwT[idx] = f2b(ef_w[c * 80 + hj]);
    }
    for (int idx = tid; idx < 128 * 96; idx += stride) {
      int c = idx / 96, hj = idx % 96;
      efhB[idx] = hj < 80 ? f2b(ef_h[c * 80 + hj]) : (u16)0;
      efwB[idx] = hj < 80 ? f2b(ef_w[c * 80 + hj]) : (u16)0;
    }
  } else {
    const int tid = (b - 144) * 256 + t;
    const int stride = 32 * 256;
    for (int idx = tid; idx < HW / 4; idx += stride)
      ((f32x4*)lbuf)[idx] = (f32x4){0.f, 0.f, 0.f, 0.f};
    for (int idx = tid; idx < HW * 96 / 8; idx += stride) {
      ((u32x4*)expA)[idx] = (u32x4){0, 0, 0, 0};
      ((u32x4*)expB)[idx] = (u32x4){0, 0, 0, 0};
    }
  }
}

// ---------------------------------------------------------------------------
// front_k: fused  x -> x1=silu(bn(conv1(x))) -> {q,k,v,p} -> LT/RT/Vv/pT.
// grid <<<200, 128>>>: 2 waves x 16 i-rows.
// ---------------------------------------------------------------------------
__global__ __launch_bounds__(128) void front_k(
    const float* __restrict__ x,
    const u16* __restrict__ w1b, const float* __restrict__ b1e,
    const u16* __restrict__ Wcat, const float* __restrict__ bcat,
    u16* __restrict__ LT, u16* __restrict__ RT, u16* __restrict__ Vv,
    u16* __restrict__ pT)
{
  __shared__ __align__(16) u16 tr[2][16][136];
  const int t = threadIdx.x, w = t >> 6, lane = t & 63, jl = lane & 15, q = lane >> 4;
  const int i0 = blockIdx.x * 32 + w * 16;

  bf16x8 afr[8];
#pragma unroll
  for (int ks = 0; ks < 8; ++ks) {
    union { bf16x8 v; u16 e[8]; } fa;
#pragma unroll
    for (int e = 0; e < 8; ++e)
      fa.e[e] = f2b(x[(size_t)(ks * 32 + q * 8 + e) * HW + i0 + jl]);
    afr[ks] = fa.v;
  }
  f32x4 acc[8];
#pragma unroll
  for (int nf = 0; nf < 8; ++nf) acc[nf] = (f32x4){0.f, 0.f, 0.f, 0.f};
#pragma unroll
  for (int ks = 0; ks < 8; ++ks)
#pragma unroll
    for (int nf = 0; nf < 8; ++nf) {
      bf16x8 b = *(const bf16x8*)(w1b + (size_t)(nf * 16 + jl) * 256 + ks * 32 + q * 8);
      acc[nf] = MFMA(afr[ks], b, acc[nf]);
    }
#pragma unroll
  for (int nf = 0; nf < 8; ++nf) {
    const int c = nf * 16 + jl;
    const float bias = b1e[c];
#pragma unroll
    for (int r = 0; r < 4; ++r)
      tr[w][q * 4 + r][c] = f2b(silu_f(acc[nf][r] + bias));
  }
  __syncthreads();
  bf16x8 xa[4];
#pragma unroll
  for (int ks = 0; ks < 4; ++ks)
    xa[ks] = *(const bf16x8*)&tr[w][jl][ks * 32 + q * 8];

#pragma unroll
  for (int nc = 0; nc < 4; ++nc) {
    f32x4 a2[8];
#pragma unroll
    for (int nf = 0; nf < 8; ++nf) a2[nf] = (f32x4){0.f, 0.f, 0.f, 0.f};
#pragma unroll
    for (int ks = 0; ks < 4; ++ks)
#pragma unroll
      for (int nf = 0; nf < 8; ++nf) {
        bf16x8 b = *(const bf16x8*)(Wcat + (size_t)(nc * 128 + nf * 16 + jl) * 128 + ks * 32 + q * 8);
        a2[nf] = MFMA(xa[ks], b, a2[nf]);
      }
    if (nc == 2) {
#pragma unroll
      for (int nf = 0; nf < 8; ++nf) {
        const int c = nf * 16 + jl;
        const float bias = bcat[256 + c];
        uint2 pk;
        pk.x = pack2(a2[nf][0] + bias, a2[nf][1] + bias);
        pk.y = pack2(a2[nf][2] + bias, a2[nf][3] + bias);
        *(uint2*)(Vv + (size_t)c * HW + i0 + q * 4) = pk;
      }
    } else {
      __syncthreads();
#pragma unroll
      for (int nf = 0; nf < 8; ++nf) {
        const int c = nf * 16 + jl;
        const float bias = bcat[nc * 128 + c];
#pragma unroll
        for (int r = 0; r < 4; ++r)
          tr[w][q * 4 + r][c] = f2b(a2[nf][r] + bias);
      }
      __syncthreads();
#pragma unroll
      for (int r = 0; r < 16; ++r) {
        unsigned val = *(const unsigned*)&tr[w][r][lane * 2];
        const size_t row = (size_t)(i0 + r);
        if (nc == 0) {
          *(unsigned*)(LT + row * 256 + lane * 2) = val;
          *(unsigned*)(RT + row * 256 + 128 + lane * 2) = val;
        } else if (nc == 1) {
          *(unsigned*)(RT + row * 256 + lane * 2) = val;
        } else {
          *(unsigned*)(pT + row * 128 + lane * 2) = val;
        }
      }
    }
  }
}

// ---------------------------------------------------------------------------
// sep2a: A = p^T.efh, B = p^T.efw via swapped MFMA (row i lane-local);
// exp in-register, row-sums sA/sB (plain stores, rows exclusive), expA/expB
// stored bf16 [i][96] (hj<80; pad pre-zeroed).  grid <<<50, 256>>>.
// ---------------------------------------------------------------------------
__global__ __launch_bounds__(256) void sep2a(
    const u16* __restrict__ pT,     // [HW][128]
    const u16* __restrict__ efhT,   // [80][128]
    const u16* __restrict__ efwT,   // [80][128]
    u16* __restrict__ expA, u16* __restrict__ expB,   // [HW][96]
    float* __restrict__ sA, float* __restrict__ sB)   // [HW]
{
  const int t = threadIdx.x, lane = t & 63, w = t >> 6, jl = lane & 15, q = lane >> 4;
  const int i0w = blockIdx.x * 128 + w * 32;

  bf16x8 pfr[2][4];
#pragma unroll
  for (int mt = 0; mt < 2; ++mt)
#pragma unroll
    for (int l = 0; l < 4; ++l)
      pfr[mt][l] = *(const bf16x8*)(pT + (size_t)(i0w + mt * 16 + jl) * 128 + l * 32 + q * 8);

  f32x4 sa[5][2], sb[5][2];
#pragma unroll
  for (int nf = 0; nf < 5; ++nf)
#pragma unroll
    for (int mt = 0; mt < 2; ++mt) {
      sa[nf][mt] = (f32x4){0.f, 0.f, 0.f, 0.f};
      sb[nf][mt] = (f32x4){0.f, 0.f, 0.f, 0.f};
    }
#pragma unroll
  for (int nf = 0; nf < 5; ++nf) {
    const int row = nf * 16 + jl;                 // hj row, < 80
#pragma unroll
    for (int l = 0; l < 4; ++l) {
      bf16x8 eh = *(const bf16x8*)(efhT + (size_t)row * 128 + l * 32 + q * 8);
      bf16x8 ew = *(const bf16x8*)(efwT + (size_t)row * 128 + l * 32 + q * 8);
      sa[nf][0] = MFMA(eh, pfr[0][l], sa[nf][0]);
      sa[nf][1] = MFMA(eh, pfr[1][l], sa[nf][1]);
      sb[nf][0] = MFMA(ew, pfr[0][l], sb[nf][0]);
      sb[nf][1] = MFMA(ew, pfr[1][l], sb[nf][1]);
    }
  }
  // thread (jl,q): A[i = i0w+mt*16+jl][hj = nf*16+q*4+r]
#pragma unroll
  for (int mt = 0; mt < 2; ++mt) {
    const int i = i0w + mt * 16 + jl;
    float ra = 0.f, rb = 0.f;
#pragma unroll
    for (int nf = 0; nf < 5; ++nf) {
      float ea[4], eb[4];
#pragma unroll
      for (int r = 0; r < 4; ++r) {
        ea[r] = __expf(sa[nf][mt][r]); ra += ea[r];
        eb[r] = __expf(sb[nf][mt][r]); rb += eb[r];
      }
      uint2 pa, pb;
      pa.x = pack2(ea[0], ea[1]); pa.y = pack2(ea[2], ea[3]);
      pb.x = pack2(eb[0], eb[1]); pb.y = pack2(eb[2], eb[3]);
      *(uint2*)(expA + (size_t)i * 96 + nf * 16 + q * 4) = pa;
      *(uint2*)(expB + (size_t)i * 96 + nf * 16 + q * 4) = pb;
    }
    ra += __shfl_xor(ra, 16); ra += __shfl_xor(ra, 32);
    rb += __shfl_xor(rb, 16); rb += __shfl_xor(rb, 32);
    if (lane < 16) { sA[i] = ra; sB[i] = rb; }
  }
}

// ---------------------------------------------------------------------------
// sep2b: U = expA.efhB^T, W = expB.efwB^T (K=96, zero-padded), then
// O2[i][c] = U/sA + W/sB  (already-normalized head-2 output).
// grid <<<50, 256>>>.
// ---------------------------------------------------------------------------
__global__ __launch_bounds__(256) void sep2b(
    const u16* __restrict__ expA, const u16* __restrict__ expB,   // [HW][96]
    const float* __restrict__ sA, const float* __restrict__ sB,   // [HW]
    const u16* __restrict__ efhB, const u16* __restrict__ efwB,   // [128][96]
    float* __restrict__ O2)                                       // [HW][128]
{
  const int t = threadIdx.x, lane = t & 63, w = t >> 6, jl = lane & 15, q = lane >> 4;
  const int i0w = blockIdx.x * 128 + w * 32;

#pragma unroll
  for (int mt = 0; mt < 2; ++mt) {
    bf16x8 fa[3], fb[3];
#pragma unroll
    for (int l = 0; l < 3; ++l) {
      fa[l] = *(const bf16x8*)(expA + (size_t)(i0w + mt * 16 + jl) * 96 + l * 32 + q * 8);
      fb[l] = *(const bf16x8*)(expB + (size_t)(i0w + mt * 16 + jl) * 96 + l * 32 + q * 8);
    }
    f32x4 oU[8], oW[8];
#pragma unroll
    for (int nf = 0; nf < 8; ++nf) {
      oU[nf] = (f32x4){0.f, 0.f, 0.f, 0.f};
      oW[nf] = (f32x4){0.f, 0.f, 0.f, 0.f};
    }
#pragma unroll
    for (int l = 0; l < 3; ++l)
#pragma unroll
      for (int nf = 0; nf < 8; ++nf) {
        bf16x8 bh = *(const bf16x8*)(efhB + (size_t)(nf * 16 + jl) * 96 + l * 32 + q * 8);
        bf16x8 bw = *(const bf16x8*)(efwB + (size_t)(nf * 16 + jl) * 96 + l * 32 + q * 8);
        oU[nf] = MFMA(fa[l], bh, oU[nf]);
        oW[nf] = MFMA(fb[l], bw, oW[nf]);
      }
    const int ib = i0w + mt * 16 + q * 4;
    float ia[4], iw[4];
#pragma unroll
    for (int r = 0; r < 4; ++r) {
      ia[r] = 1.0f / sA[ib + r];
      iw[r] = 1.0f / sB[ib + r];
    }
#pragma unroll
    for (int nf = 0; nf < 8; ++nf)
#pragma unroll
      for (int r = 0; r < 4; ++r)
        O2[(size_t)(ib + r) * 128 + nf * 16 + jl] = oU[nf][r] * ia[r] + oW[nf][r] * iw[r];
  }
}

// ---------------------------------------------------------------------------
// fused_attn: head1 flash attention, 512 thr / 8 waves, i-tile 256, jp=10,
// 5 steps of 128 j.  Rs[2] = both K-halves double-buffered (64KB); per-wave
// T 8KB (Ts 64KB); total LDS 128KB -> 1 block/CU.
// Per step: bar; score h0+h1 (128 MFMA); bar; stage both halves of next tile
// (drain covered by exp+transpose+PV); exp; wave-local transpose; fence; PV.
// Epilogue: l atomics (tiny) + exclusive partial-O stores (no atomics).
// grid <<<250, 512>>>.
// ---------------------------------------------------------------------------
__global__ __launch_bounds__(512) void fused_attn(
    const u16* __restrict__ LT,     // [HW][256]  L = [q | cp]
    const u16* __restrict__ RT,     // [HW][256]  R = [k | q]
    const u16* __restrict__ Vv,     // [128][HW]
    float* __restrict__ Opart,      // [10][HW][128]
    float* __restrict__ lv)         // [HW]
{
  __shared__ __align__(1024) u16 Rs[2][128 * 128];
  __shared__ __align__(1024) u16 Ts[8][32 * 128];
  const int t = threadIdx.x, lane = t & 63, w = t >> 6, jl = lane & 15, q = lane >> 4;
  const int it = blockIdx.x / 10, jp = blockIdx.x % 10;
  const int i0w = it * 256 + w * 32;
  u16* T0 = Ts[w];
  u16* T1 = Ts[w] + 2048;

  // L A-frags resident (B-operand of swapped score): 2 mt x 8 k-frags
  bf16x8 afr[2][8];
#pragma unroll
  for (int mt = 0; mt < 2; ++mt)
#pragma unroll
    for (int l = 0; l < 8; ++l)
      afr[mt][l] = *(const bf16x8*)(LT + (size_t)(i0w + mt * 16 + jl) * 256 + l * 32 + q * 8);

  f32x4 o[2][8];
#pragma unroll
  for (int mt = 0; mt < 2; ++mt)
#pragma unroll
    for (int cf = 0; cf < 8; ++cf) o[mt][cf] = (f32x4){0.f, 0.f, 0.f, 0.f};
  float lacc[2] = {0.f, 0.f};

  // stage BOTH 128x128 K-halves of R-tile at column jj (8 gloads/wave).
  // XOR-8 swizzle on per-lane global source, linear LDS dest.
  auto stage = [&](int jj) {
#pragma unroll
    for (int k = 0; k < 8; ++k) {
      const int b = k >> 2, cl = k & 3;
      const int cc = w * 4 + cl;                 // row-quad 0..31
      const int jr = cc * 4 + (lane >> 4);       // row 0..127
      const int cp = lane & 15;
      const int ch = (cp & ~7) | ((cp ^ jr) & 7);
      gload_lds16(RT + (size_t)(jj + jr) * 256 + b * 128 + ch * 8,
                  Rs[b] + (cc << 9));
    }
  };

  stage(jp * 640);                               // prologue

  for (int stp = 0; stp < 5; ++stp) {
    const int jj = jp * 640 + stp * 128;

    f32x4 s[8][2];
#pragma unroll
    for (int nf = 0; nf < 8; ++nf)
#pragma unroll
      for (int mt = 0; mt < 2; ++mt) s[nf][mt] = (f32x4){0.f, 0.f, 0.f, 0.f};

    __syncthreads();                             // staged tile visible (vmcnt)

    // ---- score: S^T += R . L^T over both K-halves (no barrier between)
#pragma unroll
    for (int h = 0; h < 2; ++h)
#pragma unroll
      for (int nf = 0; nf < 8; ++nf) {
        const int row = nf * 16 + jl;
#pragma unroll
        for (int l = 0; l < 4; ++l) {
          const int ch = (l * 4 + q) ^ (jl & 7); // un-swizzle
          bf16x8 b = *(const bf16x8*)(Rs[h] + row * 128 + ch * 8);
          s[nf][0] = MFMA(b, afr[0][h * 4 + l], s[nf][0]);
          s[nf][1] = MFMA(b, afr[1][h * 4 + l], s[nf][1]);
        }
      }
    __syncthreads();                             // all Rs reads done
    if (stp < 4) stage(jj + 128);                // drain covered below

    // ---- P = exp(S); per-thread rowsum partials
#pragma unroll
    for (int nf = 0; nf < 8; ++nf)
#pragma unroll
      for (int mt = 0; mt < 2; ++mt)
#pragma unroll
        for (int r = 0; r < 4; ++r) {
          float p = __expf(s[nf][mt][r]);
          s[nf][mt][r] = p;
          lacc[mt] += p;
        }

    // ---- wave-local transpose (thread owns row i=jl): b64 writes, XOR swz
#pragma unroll
    for (int mt = 0; mt < 2; ++mt)
#pragma unroll
      for (int nf = 0; nf < 8; ++nf) {
        const int cs = (nf * 4 + q) ^ ((jl & 7) << 2);
        uint2 pk;
        pk.x = pack2(s[nf][mt][0], s[nf][mt][1]);
        pk.y = pack2(s[nf][mt][2], s[nf][mt][3]);
        *(uint2*)((mt ? T1 : T0) + jl * 128 + cs * 4) = pk;
      }
    lds_fence();

    // ---- PV: O += P . V^T, V B-frags direct from global (L1-resident tile)
#pragma unroll
    for (int ks2 = 0; ks2 < 4; ++ks2) {
      const int cb = (ks2 * 8 + q * 2) ^ ((jl & 7) << 2);
      bf16x8 pa0 = *(const bf16x8*)(T0 + jl * 128 + cb * 4);
      bf16x8 pa1 = *(const bf16x8*)(T1 + jl * 128 + cb * 4);
#pragma unroll
      for (int cf = 0; cf < 8; ++cf) {
        bf16x8 bv = *(const bf16x8*)(Vv + (size_t)(cf * 16 + jl) * HW + jj + ks2 * 32 + q * 8);
        o[0][cf] = MFMA(pa0, bv, o[0][cf]);
        o[1][cf] = MFMA(pa1, bv, o[1][cf]);
      }
    }
  }

  // ---- epilogue: l rowsum (atomic, rows shared across jp) + partial-O
#pragma unroll
  for (int mt = 0; mt < 2; ++mt) {
    float rsum = lacc[mt];
    rsum += __shfl_xor(rsum, 16);
    rsum += __shfl_xor(rsum, 32);
    if (lane < 16)
      atomicAdd(&lv[i0w + mt * 16 + jl], rsum);
  }
  float* Op = Opart + (size_t)jp * HW * 128;
#pragma unroll
  for (int mt = 0; mt < 2; ++mt) {
    const int ib = i0w + mt * 16 + q * 4;
#pragma unroll
    for (int cf = 0; cf < 8; ++cf) {
      const int c = cf * 16 + jl;
#pragma unroll
      for (int r = 0; r < 4; ++r)
        Op[(size_t)(ib + r) * 128 + c] = o[mt][cf][r];
    }
  }
}

// ---------------------------------------------------------------------------
// final_k: out[d][i] = x[d][i] + silu((Sum_p Opart[p][i][:]/l1[i]).w2b + b2e)
//                              + silu(O2[i][:].w3b + b3e)
// grid dim3(100, 2), 256 thr.
// ---------------------------------------------------------------------------
__global__ __launch_bounds__(256) void final_k(
    const float* __restrict__ Opart,   // [10][HW][128]
    const float* __restrict__ O2,      // [HW][128] (pre-normalized)
    const float* __restrict__ lbuf,    // [HW]
    const u16* __restrict__ w2b, const float* __restrict__ b2e,
    const u16* __restrict__ w3b, const float* __restrict__ b3e,
    const float* __restrict__ x, float* __restrict__ outp)
{
  const int t = threadIdx.x, w = t >> 6, lane = t & 63, jl = lane & 15, q = lane >> 4;
  const int i0 = blockIdx.x * 64 + w * 16;
  const int nc = blockIdx.y;
  const int row = i0 + jl;

  const float inv1 = 1.0f / lbuf[row];
  const float* O2r = O2 + (size_t)row * 128;

  f32x4 a1[8], a2[8];
#pragma unroll
  for (int nf = 0; nf < 8; ++nf) {
    a1[nf] = (f32x4){0.f, 0.f, 0.f, 0.f};
    a2[nf] = (f32x4){0.f, 0.f, 0.f, 0.f};
  }
#pragma unroll
  for (int ks = 0; ks < 4; ++ks) {
    f32x4 s1a = (f32x4){0.f, 0.f, 0.f, 0.f};
    f32x4 s1b = (f32x4){0.f, 0.f, 0.f, 0.f};
#pragma unroll
    for (int p = 0; p < 10; ++p) {
      const float* Or = Opart + ((size_t)p * HW + row) * 128;
      s1a += *(const f32x4*)(Or + ks * 32 + q * 8);
      s1b += *(const f32x4*)(Or + ks * 32 + q * 8 + 4);
    }
    f32x4 s2a = *(const f32x4*)(O2r + ks * 32 + q * 8);
    f32x4 s2b = *(const f32x4*)(O2r + ks * 32 + q * 8 + 4);
    bf16x8 fa1 = pack8(s1a, s1b, inv1);
    bf16x8 fa2 = pack8(s2a, s2b, 1.0f);
#pragma unroll
    for (int nf = 0; nf < 8; ++nf) {
      bf16x8 b2f = *(const bf16x8*)(w2b + (size_t)(nc * 128 + nf * 16 + jl) * 128 + ks * 32 + q * 8);
      bf16x8 b3f = *(const bf16x8*)(w3b + (size_t)(nc * 128 + nf * 16 + jl) * 128 + ks * 32 + q * 8);
      a1[nf] = MFMA(fa1, b2f, a1[nf]);
      a2[nf] = MFMA(fa2, b3f, a2[nf]);
    }
  }
#pragma unroll
  for (int nf = 0; nf < 8; ++nf) {
    const int d = nc * 128 + nf * 16 + jl;
    const float bb2 = b2e[d], bb3 = b3e[d];
    const size_t base = (size_t)d * HW + i0 + q * 4;
    f32x4 xv = *(const f32x4*)(x + base);
    f32x4 rv;
#pragma unroll
    for (int r = 0; r < 4; ++r)
      rv[r] = xv[r] + silu_f(a1[nf][r] + bb2) + silu_f(a2[nf][r] + bb3);
    *(f32x4*)(outp + base) = rv;
  }
}

// ---------------------------------------------------------------------------
extern "C" void kernel_launch(void* const* d_in, const int* in_sizes, int n_in,
                              void* d_out, int out_size, void* d_ws, size_t ws_size,
                              hipStream_t stream)
{
  (void)in_sizes; (void)n_in; (void)out_size; (void)ws_size;
  const float* x   = (const float*)d_in[0];
  const float* w1  = (const float*)d_in[1];
  const float* g1  = (const float*)d_in[2];
  const float* b1  = (const float*)d_in[3];
  const float* m1  = (const float*)d_in[4];
  const float* v1  = (const float*)d_in[5];
  const float* w2  = (const float*)d_in[6];
  const float* g2  = (const float*)d_in[7];
  const float* b2  = (const float*)d_in[8];
  const float* m2  = (const float*)d_in[9];
  const float* v2  = (const float*)d_in[10];
  const float* w3  = (const float*)d_in[11];
  const float* g3  = (const float*)d_in[12];
  const float* b3  = (const float*)d_in[13];
  const float* m3  = (const float*)d_in[14];
  const float* v3  = (const float*)d_in[15];
  const float* wq  = (const float*)d_in[16];
  const float* bq  = (const float*)d_in[17];
  const float* wk  = (const float*)d_in[18];
  const float* bk  = (const float*)d_in[19];
  const float* wv  = (const float*)d_in[20];
  const float* bv  = (const float*)d_in[21];
  const float* wp  = (const float*)d_in[22];
  const float* bp  = (const float*)d_in[23];
  const float* rel_h = (const float*)d_in[24];
  const float* rel_w = (const float*)d_in[25];
  const float* ef_h  = (const float*)d_in[26];
  const float* ef_w  = (const float*)d_in[27];
  float* outp = (float*)d_out;

  char* ws = (char*)d_ws;
  size_t off = 0;
  auto alloc = [&](size_t bytes) -> void* {
    void* p = ws + off;
    off += (bytes + 511) & ~(size_t)511;
    return p;
  };
  u16* LT    = (u16*)alloc((size_t)HW * 256 * 2);
  u16* RT    = (u16*)alloc((size_t)HW * 256 * 2);
  u16* pT    = (u16*)alloc((size_t)HW * 128 * 2);
  u16* Vv    = (u16*)alloc((size_t)HW * 128 * 2);
  float* Opart = (float*)alloc((size_t)10 * HW * 128 * 4);  // 32.8 MB
  float* O2    = (float*)alloc((size_t)HW * 128 * 4);       // 3.3 MB
  float* lbuf  = (float*)alloc((size_t)HW * 4);
  u16* w1b   = (u16*)alloc(128 * 256 * 2);
  float* b1e = (float*)alloc(128 * 4);
  u16* Wcat  = (u16*)alloc(512 * 128 * 2);
  float* bcat = (float*)alloc(512 * 4);
  u16* w2b   = (u16*)alloc(256 * 128 * 2);
  float* b2e = (float*)alloc(256 * 4);
  u16* w3b   = (u16*)alloc(256 * 128 * 2);
  float* b3e = (float*)alloc(256 * 4);
  u16* efhT  = (u16*)alloc(80 * 128 * 2);
  u16* efwT  = (u16*)alloc(80 * 128 * 2);
  u16* efhB  = (u16*)alloc(128 * 96 * 2);
  u16* efwB  = (u16*)alloc(128 * 96 * 2);
  u16* expA  = (u16*)alloc((size_t)HW * 96 * 2);
  u16* expB  = (u16*)alloc((size_t)HW * 96 * 2);
  float* sA  = (float*)alloc(HW * 4);
  float* sB  = (float*)alloc(HW * 4);

  prep_all<<<176, 256, 0, stream>>>(rel_h, rel_w, ef_h, ef_w,
                                    w1, g1, b1, m1, v1, w2, g2, b2, m2, v2,
                                    w3, g3, b3, m3, v3, wq, bq, wk, bk, wv, bv, wp, bp,
                                    LT, w1b, b1e, Wcat, bcat, w2b, b2e, w3b, b3e,
                                    efhT, efwT, efhB, efwB, expA, expB, lbuf);
  front_k<<<200, 128, 0, stream>>>(x, w1b, b1e, Wcat, bcat, LT, RT, Vv, pT);
  sep2a<<<50, 256, 0, stream>>>(pT, efhT, efwT, expA, expB, sA, sB);
  sep2b<<<50, 256, 0, stream>>>(expA, expB, sA, sB, efhB, efwB, O2);
  fused_attn<<<250, 512, 0, stream>>>(LT, RT, Vv, Opart, lbuf);
  final_k<<<dim3(100, 2), 256, 0, stream>>>(Opart, O2, lbuf, w2b, b2e, w3b, b3e, x, outp);
}

// Round 6
// 249.942 us; speedup vs baseline: 2.0188x; 1.0248x over previous
//
#include <hip/hip_runtime.h>

// ============================================================================
// ExtraMHSA pipeline for MI355X (gfx950).  R11: mt=4 wave split (2i x 4j),
//   PV c-split, coalesced partial-O reduce.
//
//   prep_all : LT pos embeds, BN-fold weights->bf16, ef tables, zero l/expA/B
//   front_k  : x -> x1=silu(conv1) -> {q,k,v,p}; 1-wave blocks (400x64)
//   sep2a/b  : separable head-2 (factorized softmax); sep2b emits bf16 O2
//   fused_attn (head1): 512 thr / 8 waves = 2 wi x 4 wj; i-tile 128.
//     Wave = [64 i][32 j]: afr[4mt][8] resident (128 VGPR) -> each LDS
//     B-read feeds 4 MFMAs (score LDS traffic halved vs R10).
//     PV c-split: wave does [64 i][32 c] over full j; P shared via per-wi
//     LDS T-tiles (cross-wave, block barrier).  V traffic 4x lower.
//     Regs ~216 (afr128+s32+o32+temps) -> 2 waves/SIMD, no spill.
//     LDS 96KB (Rs 64 + T 32).  3 barriers/step.  grid <<<500, 512>>>.
//   red_k    : coalesced Sum_p Opart -> bf16 O1/l1  (replaces final_k's
//              strided 10-partial sum)
//   final_k  : out = x + silu(bn(conv2(O1))) + silu(bn(conv3(O2)))
// ============================================================================

typedef unsigned short u16;
typedef __attribute__((ext_vector_type(8))) short bf16x8;   // 8 bf16 = 4 VGPRs
typedef __attribute__((ext_vector_type(4))) float f32x4;    // MFMA C/D frag
typedef __attribute__((ext_vector_type(4))) unsigned int u32x4;

#define HW 6400
#define BN_EPS 1e-5f

__device__ __forceinline__ u16 f2b(float f) {       // fp32 -> bf16 RNE
  unsigned u = __float_as_uint(f);
  u += 0x7fffu + ((u >> 16) & 1u);
  return (u16)(u >> 16);
}
__device__ __forceinline__ unsigned pack2(float a, float b) {
  return (unsigned)f2b(a) | ((unsigned)f2b(b) << 16);
}
__device__ __forceinline__ f32x4 MFMA(bf16x8 a, bf16x8 b, f32x4 c) {
  return __builtin_amdgcn_mfma_f32_16x16x32_bf16(a, b, c, 0, 0, 0);
}
__device__ __forceinline__ float silu_f(float y) {
  return y / (1.0f + __expf(-y));
}
__device__ __forceinline__ bf16x8 pack8(f32x4 lo, f32x4 hi, float sc) {
  union { bf16x8 v; uint4 u; } r;
  r.u.x = pack2(lo[0] * sc, lo[1] * sc);
  r.u.y = pack2(lo[2] * sc, lo[3] * sc);
  r.u.z = pack2(hi[0] * sc, hi[1] * sc);
  r.u.w = pack2(hi[2] * sc, hi[3] * sc);
  return r.v;
}
// async global->LDS, 16B per lane; dst is wave-uniform base (HW adds lane*16).
__device__ __forceinline__ void gload_lds16(const u16* src, u16* dst) {
  __builtin_amdgcn_global_load_lds(
      (const __attribute__((address_space(1))) void*)src,
      (__attribute__((address_space(3))) void*)dst, 16, 0, 0);
}

// ---------------------------------------------------------------------------
// prep_all: [0,80) LT pos embeds; [80,144) weight BN-fold + ef tables;
//           [144,176) zero lbuf/expA/expB.
// ---------------------------------------------------------------------------
__global__ void prep_all(
    const float* __restrict__ rel_h, const float* __restrict__ rel_w,
    const float* __restrict__ ef_h, const float* __restrict__ ef_w,
    const float* __restrict__ w1, const float* __restrict__ g1, const float* __restrict__ b1,
    const float* __restrict__ m1, const float* __restrict__ v1,
    const float* __restrict__ w2, const float* __restrict__ g2, const float* __restrict__ b2,
    const float* __restrict__ m2, const float* __restrict__ v2,
    const float* __restrict__ w3, const float* __restrict__ g3, const float* __restrict__ b3,
    const float* __restrict__ m3, const float* __restrict__ v3,
    const float* __restrict__ wq, const float* __restrict__ bq,
    const float* __restrict__ wk, const float* __restrict__ bk,
    const float* __restrict__ wv, const float* __restrict__ bv,
    const float* __restrict__ wp, const float* __restrict__ bp,
    u16* __restrict__ LT,
    u16* __restrict__ w1b, float* __restrict__ b1e,
    u16* __restrict__ Wcat, float* __restrict__ bcat,
    u16* __restrict__ w2b, float* __restrict__ b2e,
    u16* __restrict__ w3b, float* __restrict__ b3e,
    u16* __restrict__ efhT, u16* __restrict__ efwT,
    u16* __restrict__ efhB, u16* __restrict__ efwB,
    u16* __restrict__ expA, u16* __restrict__ expB,
    float* __restrict__ lbuf)
{
  const int b = blockIdx.x;
  const int t = threadIdx.x;
  if (b < 80) {
    const int h = b;
    const int c0 = (t & 63) * 2;
    const float rh0 = rel_h[c0 * 80 + h], rh1 = rel_h[(c0 + 1) * 80 + h];
    for (int wcol = (t >> 6); wcol < 80; wcol += 4) {
      const int i = h * 80 + wcol;
      float rw0 = rel_w[c0 * 80 + wcol], rw1 = rel_w[(c0 + 1) * 80 + wcol];
      *(unsigned*)&LT[(size_t)i * 256 + 128 + c0] = pack2(rh0 + rw0, rh1 + rw1);
    }
  } else if (b < 144) {
    const int tid = (b - 80) * 256 + t;
    const int stride = 64 * 256;
    for (int idx = tid; idx < 128 * 256; idx += stride) {
      int o = idx >> 8;
      float s = g1[o] * rsqrtf(v1[o] + BN_EPS);
      w1b[idx] = f2b(w1[idx] * s);
    }
    for (int idx = tid; idx < 128; idx += stride) {
      float s = g1[idx] * rsqrtf(v1[idx] + BN_EPS);
      b1e[idx] = b1[idx] - m1[idx] * s;
    }
    for (int idx = tid; idx < 4 * 128 * 128; idx += stride) {
      int which = idx >> 14, r = idx & 16383;
      const float* src = which == 0 ? wq : which == 1 ? wk : which == 2 ? wv : wp;
      Wcat[idx] = f2b(src[r]);
    }
    for (int idx = tid; idx < 512; idx += stride) {
      int which = idx >> 7, r = idx & 127;
      const float* src = which == 0 ? bq : which == 1 ? bk : which == 2 ? bv : bp;
      bcat[idx] = src[r];
    }
    for (int idx = tid; idx < 256 * 128; idx += stride) {
      int o = idx >> 7;
      float s2 = g2[o] * rsqrtf(v2[o] + BN_EPS);
      w2b[idx] = f2b(w2[idx] * s2);
      float s3 = g3[o] * rsqrtf(v3[o] + BN_EPS);
      w3b[idx] = f2b(w3[idx] * s3);
    }
    for (int idx = tid; idx < 256; idx += stride) {
      float s2 = g2[idx] * rsqrtf(v2[idx] + BN_EPS);
      b2e[idx] = b2[idx] - m2[idx] * s2;
      float s3 = g3[idx] * rsqrtf(v3[idx] + BN_EPS);
      b3e[idx] = b3[idx] - m3[idx] * s3;
    }
    // ef tables: efhT/efwT [hj][c] (for sep2a B-op); efhB/efwB [c][96] padded
    for (int idx = tid; idx < 80 * 128; idx += stride) {
      int hj = idx >> 7, c = idx & 127;
      efhT[idx] = f2b(ef_h[c * 80 + hj]);
      efwT[idx] = f2b(ef_w[c * 80 + hj]);
    }
    for (int idx = tid; idx < 128 * 96; idx += stride) {
      int c = idx / 96, hj = idx % 96;
      efhB[idx] = hj < 80 ? f2b(ef_h[c * 80 + hj]) : (u16)0;
      efwB[idx] = hj < 80 ? f2b(ef_w[c * 80 + hj]) : (u16)0;
    }
  } else {
    const int tid = (b - 144) * 256 + t;
    const int stride = 32 * 256;
    for (int idx = tid; idx < HW / 4; idx += stride)
      ((f32x4*)lbuf)[idx] = (f32x4){0.f, 0.f, 0.f, 0.f};
    for (int idx = tid; idx < HW * 96 / 8; idx += stride) {
      ((u32x4*)expA)[idx] = (u32x4){0, 0, 0, 0};
      ((u32x4*)expB)[idx] = (u32x4){0, 0, 0, 0};
    }
  }
}

// ---------------------------------------------------------------------------
// front_k: fused  x -> x1=silu(bn(conv1(x))) -> {q,k,v,p} -> LT/RT/Vv/pT.
// R11: 1-wave blocks (higher blocks/CU for latency hiding).  grid <<<400,64>>>.
// ---------------------------------------------------------------------------
__global__ __launch_bounds__(64) void front_k(
    const float* __restrict__ x,
    const u16* __restrict__ w1b, const float* __restrict__ b1e,
    const u16* __restrict__ Wcat, const float* __restrict__ bcat,
    u16* __restrict__ LT, u16* __restrict__ RT, u16* __restrict__ Vv,
    u16* __restrict__ pT)
{
  __shared__ __align__(16) u16 tr[16][136];
  const int t = threadIdx.x, lane = t & 63, jl = lane & 15, q = lane >> 4;
  const int i0 = blockIdx.x * 16;

  bf16x8 afr[8];
#pragma unroll
  for (int ks = 0; ks < 8; ++ks) {
    union { bf16x8 v; u16 e[8]; } fa;
#pragma unroll
    for (int e = 0; e < 8; ++e)
      fa.e[e] = f2b(x[(size_t)(ks * 32 + q * 8 + e) * HW + i0 + jl]);
    afr[ks] = fa.v;
  }
  f32x4 acc[8];
#pragma unroll
  for (int nf = 0; nf < 8; ++nf) acc[nf] = (f32x4){0.f, 0.f, 0.f, 0.f};
#pragma unroll
  for (int ks = 0; ks < 8; ++ks)
#pragma unroll
    for (int nf = 0; nf < 8; ++nf) {
      bf16x8 b = *(const bf16x8*)(w1b + (size_t)(nf * 16 + jl) * 256 + ks * 32 + q * 8);
      acc[nf] = MFMA(afr[ks], b, acc[nf]);
    }
#pragma unroll
  for (int nf = 0; nf < 8; ++nf) {
    const int c = nf * 16 + jl;
    const float bias = b1e[c];
#pragma unroll
    for (int r = 0; r < 4; ++r)
      tr[q * 4 + r][c] = f2b(silu_f(acc[nf][r] + bias));
  }
  __syncthreads();
  bf16x8 xa[4];
#pragma unroll
  for (int ks = 0; ks < 4; ++ks)
    xa[ks] = *(const bf16x8*)&tr[jl][ks * 32 + q * 8];

#pragma unroll
  for (int nc = 0; nc < 4; ++nc) {
    f32x4 a2[8];
#pragma unroll
    for (int nf = 0; nf < 8; ++nf) a2[nf] = (f32x4){0.f, 0.f, 0.f, 0.f};
#pragma unroll
    for (int ks = 0; ks < 4; ++ks)
#pragma unroll
      for (int nf = 0; nf < 8; ++nf) {
        bf16x8 b = *(const bf16x8*)(Wcat + (size_t)(nc * 128 + nf * 16 + jl) * 128 + ks * 32 + q * 8);
        a2[nf] = MFMA(xa[ks], b, a2[nf]);
      }
    if (nc == 2) {
#pragma unroll
      for (int nf = 0; nf < 8; ++nf) {
        const int c = nf * 16 + jl;
        const float bias = bcat[256 + c];
        uint2 pk;
        pk.x = pack2(a2[nf][0] + bias, a2[nf][1] + bias);
        pk.y = pack2(a2[nf][2] + bias, a2[nf][3] + bias);
        *(uint2*)(Vv + (size_t)c * HW + i0 + q * 4) = pk;
      }
    } else {
      __syncthreads();
#pragma unroll
      for (int nf = 0; nf < 8; ++nf) {
        const int c = nf * 16 + jl;
        const float bias = bcat[nc * 128 + c];
#pragma unroll
        for (int r = 0; r < 4; ++r)
          tr[q * 4 + r][c] = f2b(a2[nf][r] + bias);
      }
      __syncthreads();
#pragma unroll
      for (int r = 0; r < 16; ++r) {
        unsigned val = *(const unsigned*)&tr[r][lane * 2];
        const size_t row = (size_t)(i0 + r);
        if (nc == 0) {
          *(unsigned*)(LT + row * 256 + lane * 2) = val;
          *(unsigned*)(RT + row * 256 + 128 + lane * 2) = val;
        } else if (nc == 1) {
          *(unsigned*)(RT + row * 256 + lane * 2) = val;
        } else {
          *(unsigned*)(pT + row * 128 + lane * 2) = val;
        }
      }
    }
  }
}

// ---------------------------------------------------------------------------
// sep2a: A = p^T.efh, B = p^T.efw via swapped MFMA (row i lane-local);
// exp in-register, row-sums sA/sB, expA/expB bf16 [i][96].  grid <<<50,256>>>.
// ---------------------------------------------------------------------------
__global__ __launch_bounds__(256) void sep2a(
    const u16* __restrict__ pT,     // [HW][128]
    const u16* __restrict__ efhT,   // [80][128]
    const u16* __restrict__ efwT,   // [80][128]
    u16* __restrict__ expA, u16* __restrict__ expB,   // [HW][96]
    float* __restrict__ sA, float* __restrict__ sB)   // [HW]
{
  const int t = threadIdx.x, lane = t & 63, w = t >> 6, jl = lane & 15, q = lane >> 4;
  const int i0w = blockIdx.x * 128 + w * 32;

  bf16x8 pfr[2][4];
#pragma unroll
  for (int mt = 0; mt < 2; ++mt)
#pragma unroll
    for (int l = 0; l < 4; ++l)
      pfr[mt][l] = *(const bf16x8*)(pT + (size_t)(i0w + mt * 16 + jl) * 128 + l * 32 + q * 8);

  f32x4 sa[5][2], sb[5][2];
#pragma unroll
  for (int nf = 0; nf < 5; ++nf)
#pragma unroll
    for (int mt = 0; mt < 2; ++mt) {
      sa[nf][mt] = (f32x4){0.f, 0.f, 0.f, 0.f};
      sb[nf][mt] = (f32x4){0.f, 0.f, 0.f, 0.f};
    }
#pragma unroll
  for (int nf = 0; nf < 5; ++nf) {
    const int row = nf * 16 + jl;                 // hj row, < 80
#pragma unroll
    for (int l = 0; l < 4; ++l) {
      bf16x8 eh = *(const bf16x8*)(efhT + (size_t)row * 128 + l * 32 + q * 8);
      bf16x8 ew = *(const bf16x8*)(efwT + (size_t)row * 128 + l * 32 + q * 8);
      sa[nf][0] = MFMA(eh, pfr[0][l], sa[nf][0]);
      sa[nf][1] = MFMA(eh, pfr[1][l], sa[nf][1]);
      sb[nf][0] = MFMA(ew, pfr[0][l], sb[nf][0]);
      sb[nf][1] = MFMA(ew, pfr[1][l], sb[nf][1]);
    }
  }
#pragma unroll
  for (int mt = 0; mt < 2; ++mt) {
    const int i = i0w + mt * 16 + jl;
    float ra = 0.f, rb = 0.f;
#pragma unroll
    for (int nf = 0; nf < 5; ++nf) {
      float ea[4], eb[4];
#pragma unroll
      for (int r = 0; r < 4; ++r) {
        ea[r] = __expf(sa[nf][mt][r]); ra += ea[r];
        eb[r] = __expf(sb[nf][mt][r]); rb += eb[r];
      }
      uint2 pa, pb;
      pa.x = pack2(ea[0], ea[1]); pa.y = pack2(ea[2], ea[3]);
      pb.x = pack2(eb[0], eb[1]); pb.y = pack2(eb[2], eb[3]);
      *(uint2*)(expA + (size_t)i * 96 + nf * 16 + q * 4) = pa;
      *(uint2*)(expB + (size_t)i * 96 + nf * 16 + q * 4) = pb;
    }
    ra += __shfl_xor(ra, 16); ra += __shfl_xor(ra, 32);
    rb += __shfl_xor(rb, 16); rb += __shfl_xor(rb, 32);
    if (lane < 16) { sA[i] = ra; sB[i] = rb; }
  }
}

// ---------------------------------------------------------------------------
// sep2b: U = expA.efhB^T, W = expB.efwB^T (K=96), Ob2 = bf16(U/sA + W/sB).
// grid <<<50, 256>>>.
// ---------------------------------------------------------------------------
__global__ __launch_bounds__(256) void sep2b(
    const u16* __restrict__ expA, const u16* __restrict__ expB,   // [HW][96]
    const float* __restrict__ sA, const float* __restrict__ sB,   // [HW]
    const u16* __restrict__ efhB, const u16* __restrict__ efwB,   // [128][96]
    u16* __restrict__ Ob2)                                        // [HW][128] bf16
{
  const int t = threadIdx.x, lane = t & 63, w = t >> 6, jl = lane & 15, q = lane >> 4;
  const int i0w = blockIdx.x * 128 + w * 32;

#pragma unroll
  for (int mt = 0; mt < 2; ++mt) {
    bf16x8 fa[3], fb[3];
#pragma unroll
    for (int l = 0; l < 3; ++l) {
      fa[l] = *(const bf16x8*)(expA + (size_t)(i0w + mt * 16 + jl) * 96 + l * 32 + q * 8);
      fb[l] = *(const bf16x8*)(expB + (size_t)(i0w + mt * 16 + jl) * 96 + l * 32 + q * 8);
    }
    f32x4 oU[8], oW[8];
#pragma unroll
    for (int nf = 0; nf < 8; ++nf) {
      oU[nf] = (f32x4){0.f, 0.f, 0.f, 0.f};
      oW[nf] = (f32x4){0.f, 0.f, 0.f, 0.f};
    }
#pragma unroll
    for (int l = 0; l < 3; ++l)
#pragma unroll
      for (int nf = 0; nf < 8; ++nf) {
        bf16x8 bh = *(const bf16x8*)(efhB + (size_t)(nf * 16 + jl) * 96 + l * 32 + q * 8);
        bf16x8 bw = *(const bf16x8*)(efwB + (size_t)(nf * 16 + jl) * 96 + l * 32 + q * 8);
        oU[nf] = MFMA(fa[l], bh, oU[nf]);
        oW[nf] = MFMA(fb[l], bw, oW[nf]);
      }
    const int ib = i0w + mt * 16 + q * 4;
    float ia[4], iw[4];
#pragma unroll
    for (int r = 0; r < 4; ++r) {
      ia[r] = 1.0f / sA[ib + r];
      iw[r] = 1.0f / sB[ib + r];
    }
#pragma unroll
    for (int nf = 0; nf < 8; ++nf)
#pragma unroll
      for (int r = 0; r < 4; ++r)
        Ob2[(size_t)(ib + r) * 128 + nf * 16 + jl] =
            f2b(oU[nf][r] * ia[r] + oW[nf][r] * iw[r]);
  }
}

// ---------------------------------------------------------------------------
// fused_attn: head1.  512 thr / 8 waves = 2 wi x 4 wj.  i-tile 128.
// Wave = [64 i (4 mt)][32 j (2 nf)] for score; [64 i][32 c] full-j for PV.
// LDS: Rs[2] 64KB (both K-halves, stage-ahead), T[2 wi][64][128] 32KB.
// Per step: bar(staged+T free); score; bar(Rs done); stage next; exp;
//           transpose->T[wi]; bar(T visible); PV.
// grid <<<500, 512>>>.
// ---------------------------------------------------------------------------
__global__ __launch_bounds__(512, 2) void fused_attn(
    const u16* __restrict__ LT,     // [HW][256]  L = [q | cp]
    const u16* __restrict__ RT,     // [HW][256]  R = [k | q]
    const u16* __restrict__ Vv,     // [128][HW]
    float* __restrict__ Opart,      // [10][HW][128]
    float* __restrict__ lv)         // [HW]
{
  __shared__ __align__(1024) u16 Rs[2][128 * 128];
  __shared__ __align__(1024) u16 Ts[2][64 * 128];
  const int t = threadIdx.x, lane = t & 63, w = t >> 6, jl = lane & 15, q = lane >> 4;
  const int it = blockIdx.x / 10, jp = blockIdx.x % 10;
  const int wi = w & 1, wj = w >> 1;             // 2 i-groups x 4 j-quarters
  const int i0w = it * 128 + wi * 64;
  u16* Tw = Ts[wi];

  // L A-frags resident (B-operand of swapped score): 4 mt x 8 k-frags = 128 VGPR
  bf16x8 afr[4][8];
#pragma unroll
  for (int mt = 0; mt < 4; ++mt)
#pragma unroll
    for (int l = 0; l < 8; ++l)
      afr[mt][l] = *(const bf16x8*)(LT + (size_t)(i0w + mt * 16 + jl) * 256 + l * 32 + q * 8);

  f32x4 o[4][2];                                 // [mt][cf] c-quarter partial O
#pragma unroll
  for (int mt = 0; mt < 4; ++mt)
#pragma unroll
    for (int cf = 0; cf < 2; ++cf) o[mt][cf] = (f32x4){0.f, 0.f, 0.f, 0.f};
  float lacc[4] = {0.f, 0.f, 0.f, 0.f};

  // stage BOTH 128x128 K-halves of R-tile at column jj (8 gloads/wave).
  auto stage = [&](int jj) {
#pragma unroll
    for (int k = 0; k < 8; ++k) {
      const int b = k >> 2, cl = k & 3;
      const int cc = w * 4 + cl;                 // row-quad 0..31
      const int jr = cc * 4 + (lane >> 4);       // row 0..127
      const int cp = lane & 15;
      const int ch = (cp & ~7) | ((cp ^ jr) & 7);
      gload_lds16(RT + (size_t)(jj + jr) * 256 + b * 128 + ch * 8,
                  Rs[b] + (cc << 9));
    }
  };

  stage(jp * 640);                               // prologue

  for (int stp = 0; stp < 5; ++stp) {
    const int jj = jp * 640 + stp * 128;

    f32x4 s[2][4];                               // [nf (j-quarter)][mt]
#pragma unroll
    for (int nf = 0; nf < 2; ++nf)
#pragma unroll
      for (int mt = 0; mt < 4; ++mt) s[nf][mt] = (f32x4){0.f, 0.f, 0.f, 0.f};

    __syncthreads();                             // staged visible; prev T reads done

    // ---- score: S^T += R . L^T, wave j-quarter, 16 LDS reads feed 64 MFMA
#pragma unroll
    for (int h = 0; h < 2; ++h)
#pragma unroll
      for (int nf = 0; nf < 2; ++nf) {
        const int row = wj * 32 + nf * 16 + jl;
#pragma unroll
        for (int l = 0; l < 4; ++l) {
          const int ch = (l * 4 + q) ^ (jl & 7); // un-swizzle
          bf16x8 b = *(const bf16x8*)(Rs[h] + row * 128 + ch * 8);
          s[nf][0] = MFMA(b, afr[0][h * 4 + l], s[nf][0]);
          s[nf][1] = MFMA(b, afr[1][h * 4 + l], s[nf][1]);
          s[nf][2] = MFMA(b, afr[2][h * 4 + l], s[nf][2]);
          s[nf][3] = MFMA(b, afr[3][h * 4 + l], s[nf][3]);
        }
      }
    __syncthreads();                             // all Rs reads done
    if (stp < 4) stage(jj + 128);                // drain hides under exp/transpose

    // ---- P = exp(S); rowsum partials (thread's j-slice)
#pragma unroll
    for (int nf = 0; nf < 2; ++nf)
#pragma unroll
      for (int mt = 0; mt < 4; ++mt)
#pragma unroll
        for (int r = 0; r < 4; ++r) {
          float p = __expf(s[nf][mt][r]);
          s[nf][mt][r] = p;
          lacc[mt] += p;
        }

    // ---- transpose P -> T[wi] (j-quarter columns), chunk-XOR swizzle
    // thread holds P[i = mt*16+jl][j = wj*32+nf*16+q*4 .. +3]
#pragma unroll
    for (int mt = 0; mt < 4; ++mt)
#pragma unroll
      for (int nf = 0; nf < 2; ++nf) {
        const int row = mt * 16 + jl;
        const int cs = (wj * 8 + nf * 4 + q) ^ ((jl & 7) << 2);
        uint2 pk;
        pk.x = pack2(s[nf][mt][0], s[nf][mt][1]);
        pk.y = pack2(s[nf][mt][2], s[nf][mt][3]);
        *(uint2*)(Tw + row * 128 + cs * 4) = pk;
      }
    __syncthreads();                             // T visible across wj waves

    // ---- PV: wave does [64 i][32 c] over full j (K=128)
#pragma unroll
    for (int ks2 = 0; ks2 < 4; ++ks2) {
      bf16x8 bv0 = *(const bf16x8*)(Vv + (size_t)(wj * 32 + jl) * HW + jj + ks2 * 32 + q * 8);
      bf16x8 bv1 = *(const bf16x8*)(Vv + (size_t)(wj * 32 + 16 + jl) * HW + jj + ks2 * 32 + q * 8);
      const int cb = (ks2 * 8 + q * 2) ^ ((jl & 7) << 2);
#pragma unroll
      for (int mt = 0; mt < 4; ++mt) {
        bf16x8 pa = *(const bf16x8*)(Tw + (mt * 16 + jl) * 128 + cb * 4);
        o[mt][0] = MFMA(pa, bv0, o[mt][0]);
        o[mt][1] = MFMA(pa, bv1, o[mt][1]);
      }
    }
  }

  // ---- epilogue: l rowsum (atomic; summed across wj waves & jp blocks)
#pragma unroll
  for (int mt = 0; mt < 4; ++mt) {
    float rsum = lacc[mt];
    rsum += __shfl_xor(rsum, 16);
    rsum += __shfl_xor(rsum, 32);
    if (lane < 16)
      atomicAdd(&lv[i0w + mt * 16 + jl], rsum);
  }
  // partial-O: exclusive rows (wi,mt) x cols (wj,cf) per jp
  float* Op = Opart + (size_t)jp * HW * 128;
#pragma unroll
  for (int mt = 0; mt < 4; ++mt) {
    const int ib = i0w + mt * 16 + q * 4;
#pragma unroll
    for (int cf = 0; cf < 2; ++cf) {
      const int c = wj * 32 + cf * 16 + jl;
#pragma unroll
      for (int r = 0; r < 4; ++r)
        Op[(size_t)(ib + r) * 128 + c] = o[mt][cf][r];
    }
  }
}

// ---------------------------------------------------------------------------
// red_k: Ob1[i][c] = bf16( (Sum_p Opart[p][i][c]) / l1[i] ).  Fully coalesced.
// grid <<<400, 256>>> (102400 threads x 8 c each).
// ---------------------------------------------------------------------------
__global__ __launch_bounds__(256) void red_k(
    const float* __restrict__ Opart,   // [10][HW][128]
    const float* __restrict__ lv,      // [HW]
    u16* __restrict__ Ob1)             // [HW][128] bf16
{
  const int idx = blockIdx.x * 256 + threadIdx.x;
  const int i = idx >> 4;
  const int c0 = (idx & 15) * 8;
  f32x4 a = {0.f, 0.f, 0.f, 0.f}, b = {0.f, 0.f, 0.f, 0.f};
#pragma unroll
  for (int p = 0; p < 10; ++p) {
    const float* src = Opart + ((size_t)p * HW + i) * 128 + c0;
    a += *(const f32x4*)src;
    b += *(const f32x4*)(src + 4);
  }
  const float inv = 1.0f / lv[i];
  *(bf16x8*)(Ob1 + (size_t)i * 128 + c0) = pack8(a, b, inv);
}

// ---------------------------------------------------------------------------
// final_k: out[d][i] = x[d][i] + silu(Ob1.w2b + b2e) + silu(Ob2.w3b + b3e).
// A-frags loaded directly as bf16.  grid dim3(100, 2), 256 thr.
// ---------------------------------------------------------------------------
__global__ __launch_bounds__(256) void final_k(
    const u16* __restrict__ Ob1,       // [HW][128] bf16 (pre-normalized)
    const u16* __restrict__ Ob2,       // [HW][128] bf16 (pre-normalized)
    const u16* __restrict__ w2b, const float* __restrict__ b2e,
    const u16* __restrict__ w3b, const float* __restrict__ b3e,
    const float* __restrict__ x, float* __restrict__ outp)
{
  const int t = threadIdx.x, w = t >> 6, lane = t & 63, jl = lane & 15, q = lane >> 4;
  const int i0 = blockIdx.x * 64 + w * 16;
  const int nc = blockIdx.y;
  const int row = i0 + jl;

  f32x4 a1[8], a2[8];
#pragma unroll
  for (int nf = 0; nf < 8; ++nf) {
    a1[nf] = (f32x4){0.f, 0.f, 0.f, 0.f};
    a2[nf] = (f32x4){0.f, 0.f, 0.f, 0.f};
  }
#pragma unroll
  for (int ks = 0; ks < 4; ++ks) {
    bf16x8 fa1 = *(const bf16x8*)(Ob1 + (size_t)row * 128 + ks * 32 + q * 8);
    bf16x8 fa2 = *(const bf16x8*)(Ob2 + (size_t)row * 128 + ks * 32 + q * 8);
#pragma unroll
    for (int nf = 0; nf < 8; ++nf) {
      bf16x8 b2f = *(const bf16x8*)(w2b + (size_t)(nc * 128 + nf * 16 + jl) * 128 + ks * 32 + q * 8);
      bf16x8 b3f = *(const bf16x8*)(w3b + (size_t)(nc * 128 + nf * 16 + jl) * 128 + ks * 32 + q * 8);
      a1[nf] = MFMA(fa1, b2f, a1[nf]);
      a2[nf] = MFMA(fa2, b3f, a2[nf]);
    }
  }
#pragma unroll
  for (int nf = 0; nf < 8; ++nf) {
    const int d = nc * 128 + nf * 16 + jl;
    const float bb2 = b2e[d], bb3 = b3e[d];
    const size_t base = (size_t)d * HW + i0 + q * 4;
    f32x4 xv = *(const f32x4*)(x + base);
    f32x4 rv;
#pragma unroll
    for (int r = 0; r < 4; ++r)
      rv[r] = xv[r] + silu_f(a1[nf][r] + bb2) + silu_f(a2[nf][r] + bb3);
    *(f32x4*)(outp + base) = rv;
  }
}

// ---------------------------------------------------------------------------
extern "C" void kernel_launch(void* const* d_in, const int* in_sizes, int n_in,
                              void* d_out, int out_size, void* d_ws, size_t ws_size,
                              hipStream_t stream)
{
  (void)in_sizes; (void)n_in; (void)out_size; (void)ws_size;
  const float* x   = (const float*)d_in[0];
  const float* w1  = (const float*)d_in[1];
  const float* g1  = (const float*)d_in[2];
  const float* b1  = (const float*)d_in[3];
  const float* m1  = (const float*)d_in[4];
  const float* v1  = (const float*)d_in[5];
  const float* w2  = (const float*)d_in[6];
  const float* g2  = (const float*)d_in[7];
  const float* b2  = (const float*)d_in[8];
  const float* m2  = (const float*)d_in[9];
  const float* v2  = (const float*)d_in[10];
  const float* w3  = (const float*)d_in[11];
  const float* g3  = (const float*)d_in[12];
  const float* b3  = (const float*)d_in[13];
  const float* m3  = (const float*)d_in[14];
  const float* v3  = (const float*)d_in[15];
  const float* wq  = (const float*)d_in[16];
  const float* bq  = (const float*)d_in[17];
  const float* wk  = (const float*)d_in[18];
  const float* bk  = (const float*)d_in[19];
  const float* wv  = (const float*)d_in[20];
  const float* bv  = (const float*)d_in[21];
  const float* wp  = (const float*)d_in[22];
  const float* bp  = (const float*)d_in[23];
  const float* rel_h = (const float*)d_in[24];
  const float* rel_w = (const float*)d_in[25];
  const float* ef_h  = (const float*)d_in[26];
  const float* ef_w  = (const float*)d_in[27];
  float* outp = (float*)d_out;

  char* ws = (char*)d_ws;
  size_t off = 0;
  auto alloc = [&](size_t bytes) -> void* {
    void* p = ws + off;
    off += (bytes + 511) & ~(size_t)511;
    return p;
  };
  u16* LT    = (u16*)alloc((size_t)HW * 256 * 2);
  u16* RT    = (u16*)alloc((size_t)HW * 256 * 2);
  u16* pT    = (u16*)alloc((size_t)HW * 128 * 2);
  u16* Vv    = (u16*)alloc((size_t)HW * 128 * 2);
  float* Opart = (float*)alloc((size_t)10 * HW * 128 * 4);  // 32.8 MB
  u16* Ob1   = (u16*)alloc((size_t)HW * 128 * 2);
  u16* Ob2   = (u16*)alloc((size_t)HW * 128 * 2);
  float* lbuf  = (float*)alloc((size_t)HW * 4);
  u16* w1b   = (u16*)alloc(128 * 256 * 2);
  float* b1e = (float*)alloc(128 * 4);
  u16* Wcat  = (u16*)alloc(512 * 128 * 2);
  float* bcat = (float*)alloc(512 * 4);
  u16* w2b   = (u16*)alloc(256 * 128 * 2);
  float* b2e = (float*)alloc(256 * 4);
  u16* w3b   = (u16*)alloc(256 * 128 * 2);
  float* b3e = (float*)alloc(256 * 4);
  u16* efhT  = (u16*)alloc(80 * 128 * 2);
  u16* efwT  = (u16*)alloc(80 * 128 * 2);
  u16* efhB  = (u16*)alloc(128 * 96 * 2);
  u16* efwB  = (u16*)alloc(128 * 96 * 2);
  u16* expA  = (u16*)alloc((size_t)HW * 96 * 2);
  u16* expB  = (u16*)alloc((size_t)HW * 96 * 2);
  float* sA  = (float*)alloc(HW * 4);
  float* sB  = (float*)alloc(HW * 4);

  prep_all<<<176, 256, 0, stream>>>(rel_h, rel_w, ef_h, ef_w,
                                    w1, g1, b1, m1, v1, w2, g2, b2, m2, v2,
                                    w3, g3, b3, m3, v3, wq, bq, wk, bk, wv, bv, wp, bp,
                                    LT, w1b, b1e, Wcat, bcat, w2b, b2e, w3b, b3e,
                                    efhT, efwT, efhB, efwB, expA, expB, lbuf);
  front_k<<<400, 64, 0, stream>>>(x, w1b, b1e, Wcat, bcat, LT, RT, Vv, pT);
  sep2a<<<50, 256, 0, stream>>>(pT, efhT, efwT, expA, expB, sA, sB);
  sep2b<<<50, 256, 0, stream>>>(expA, expB, sA, sB, efhB, efwB, Ob2);
  fused_attn<<<500, 512, 0, stream>>>(LT, RT, Vv, Opart, lbuf);
  red_k<<<400, 256, 0, stream>>>(Opart, lbuf, Ob1);
  final_k<<<dim3(100, 2), 256, 0, stream>>>(Ob1, Ob2, w2b, b2e, w3b, b3e, x, outp);
}